// Round 8
// baseline (697.920 us; speedup 1.0000x reference)
//
#include <hip/hip_runtime.h>
#include <cstdint>
#include <cstddef>

#define B8 8
#define LSEQ 2048
#define LC 2051
#define DMODEL 1024
#define DIM 2048
#define LPAD 2054           // 3 + 2048 + 3 zero-padded rows per batch
#define M2 16408            // B8*LC valid rows
#define M2P 16512           // padded to multiple of 128
#define CS 32               // scan chunk size
#define NCH 65              // ceil(2051/32)

typedef __attribute__((ext_vector_type(8))) short short8;
typedef __attribute__((ext_vector_type(4))) float floatx4;
typedef __attribute__((ext_vector_type(2))) float float2v;

// A_n = -exp(-n/3), n=0..15
__device__ __constant__ float AeT[16] = {
  -1.0f,          -0.71653131f, -0.51341712f, -0.36787944f,
  -0.26359714f,   -0.18887560f, -0.13533528f, -0.09697208f,
  -0.06948345f,   -0.04978707f, -0.03567399f, -0.02556154f,
  -0.01831564f,   -0.01312373f, -0.00940356f, -0.00673795f};

#define LOG2E 1.44269504088896f

__device__ __forceinline__ float bf2f(unsigned short h) {
  union { unsigned int u; float f; } v; v.u = ((unsigned int)h) << 16; return v.f;
}
__device__ __forceinline__ unsigned short f2bf(float f) {
  union { float f; unsigned int u; } v; v.f = f;
  unsigned int r = (v.u + 0x7FFFu + ((v.u >> 16) & 1u)) >> 16;
  return (unsigned short)r;
}

// ---- packed fp32 helpers (VOP3P). One scalar operand allowed per instr. ----
__device__ __forceinline__ float2v pk_mul_vv(float2v a, float2v b) {
  float2v d; asm("v_pk_mul_f32 %0, %1, %2" : "=v"(d) : "v"(a), "v"(b)); return d;
}
__device__ __forceinline__ float2v pk_mul_sv(float2v bs, float2v a) {   // bs wave-uniform (SGPR)
  float2v d; asm("v_pk_mul_f32 %0, %1, %2" : "=v"(d) : "s"(bs), "v"(a)); return d;
}
__device__ __forceinline__ float2v pk_fma_vvv(float2v a, float2v b, float2v c) {
  float2v d; asm("v_pk_fma_f32 %0, %1, %2, %3" : "=v"(d) : "v"(a), "v"(b), "v"(c)); return d;
}
__device__ __forceinline__ float2v pk_fma_vsv(float2v a, float2v bs, float2v c) { // bs uniform
  float2v d; asm("v_pk_fma_f32 %0, %1, %2, %3" : "=v"(d) : "v"(a), "s"(bs), "v"(c)); return d;
}
__device__ __forceinline__ float2v pk_add_vv(float2v a, float2v b) {
  float2v d; asm("v_pk_add_f32 %0, %1, %2" : "=v"(d) : "v"(a), "v"(b)); return d;
}
__device__ __forceinline__ float exp2_raw(float x) {   // 2^x
  float d; asm("v_exp_f32 %0, %1" : "=v"(d) : "v"(x)); return d;
}

// ---------------- fp32 -> bf16 convert (8 elems/thread) ----------------
__global__ __launch_bounds__(256) void cvt_f32_bf16(const float* __restrict__ in,
                                                    unsigned short* __restrict__ out,
                                                    int n8) {
  int i = blockIdx.x * 256 + threadIdx.x;
  if (i >= n8) return;
  const float4* p = (const float4*)in + (size_t)i * 2;
  float4 a = p[0], b = p[1];
  uint4 o;
  o.x = (unsigned)f2bf(a.x) | ((unsigned)f2bf(a.y) << 16);
  o.y = (unsigned)f2bf(a.z) | ((unsigned)f2bf(a.w) << 16);
  o.z = (unsigned)f2bf(b.x) | ((unsigned)f2bf(b.y) << 16);
  o.w = (unsigned)f2bf(b.z) | ((unsigned)f2bf(b.w) << 16);
  *((uint4*)out + i) = o;
}

// ---------------- zero the 6 pad rows per batch of xp ----------------
__global__ __launch_bounds__(256) void zero_pads(unsigned short* __restrict__ xp) {
  int i = blockIdx.x * 256 + threadIdx.x;      // 0..12287
  int b = i / 1536;
  int r6 = (i % 1536) / 256;
  int dd = (i % 256) * 8;
  int row = (r6 < 3) ? r6 : (2048 + r6);       // 0,1,2,2051,2052,2053
  uint4 z = make_uint4(0, 0, 0, 0);
  *(uint4*)(xp + ((size_t)b * LPAD + row) * DIM + dd) = z;
}

// ---------------- depthwise conv1d: xp(padded bf16) -> xc bf16 ----------------
__global__ __launch_bounds__(256) void conv_kernel(const unsigned short* __restrict__ xp,
                                                   const float* __restrict__ conv_w,
                                                   const float* __restrict__ conv_b,
                                                   unsigned short* __restrict__ xc) {
  const int tc = blockIdx.x, b = blockIdx.y;
  const int d0 = threadIdx.x * 8;
  const unsigned short* base = xp + ((size_t)b * LPAD + tc) * DIM + d0;

  float4 cw[8];
#pragma unroll
  for (int j = 0; j < 8; ++j) cw[j] = *(const float4*)(conv_w + (size_t)(d0 + j) * 4);

  float acc[8];
  const float4* cb4 = (const float4*)(conv_b + d0);
  float4 cb0 = cb4[0], cb1 = cb4[1];
  acc[0] = cb0.x; acc[1] = cb0.y; acc[2] = cb0.z; acc[3] = cb0.w;
  acc[4] = cb1.x; acc[5] = cb1.y; acc[6] = cb1.z; acc[7] = cb1.w;

#pragma unroll
  for (int k = 0; k < 4; ++k) {
    uint4 v = *(const uint4*)(base + (size_t)k * DIM);
    unsigned short e[8];
    e[0] = v.x & 0xffff; e[1] = v.x >> 16; e[2] = v.y & 0xffff; e[3] = v.y >> 16;
    e[4] = v.z & 0xffff; e[5] = v.z >> 16; e[6] = v.w & 0xffff; e[7] = v.w >> 16;
#pragma unroll
    for (int j = 0; j < 8; ++j)
      acc[j] = fmaf(bf2f(e[j]), ((const float*)&cw[j])[k], acc[j]);
  }
  uint4 o;
  o.x = (unsigned)f2bf(acc[0]) | ((unsigned)f2bf(acc[1]) << 16);
  o.y = (unsigned)f2bf(acc[2]) | ((unsigned)f2bf(acc[3]) << 16);
  o.z = (unsigned)f2bf(acc[4]) | ((unsigned)f2bf(acc[5]) << 16);
  o.w = (unsigned)f2bf(acc[6]) | ((unsigned)f2bf(acc[7]) << 16);
  *(uint4*)(xc + ((size_t)b * LC + tc) * DIM + d0) = o;
}

#define GAS(p) ((const __attribute__((address_space(1))) void*)(p))
#define LAS(p) ((__attribute__((address_space(3))) void*)(p))

// ---------------- bf16 MFMA GEMM (m97 structure, proven) ----------------
// Block mapping: DIRECT=0 -> XCD-banded 1D remap (bm = xcd*LX + j%LX, bn = j/LX;
//   grid MUST be 8*LX*NBN and NBM == 8*LX for perfect balance).
// DIRECT=1 -> plain: bm = gid%NBM, bn = gid/NBM (for small tail launches).
// Row base = (MOFF + bm) * 128.
// MODE 0: gemm1 -> xp padded bf16, +b_in      (N=2048)
// MODE 1: xdbl  -> fp32 [M2][48], cols<48
// MODE 2: out   -> fp32 [M2][1024], +b_out
template <int MODE, int NBM, int NBN, int LX, int MOFF, int DIRECT>
__global__ __launch_bounds__(256) void gemm_bt(const unsigned short* __restrict__ A,
                                               const unsigned short* __restrict__ Bw,
                                               const float* __restrict__ bias,
                                               void* __restrict__ Cout, int K) {
  int bm, bn;
  if constexpr (DIRECT) {
    bm = (int)blockIdx.x % NBM;
    bn = (int)blockIdx.x / NBM;
  } else {
    const int gid = blockIdx.x;
    const int xcd = gid & 7;
    const int j = gid >> 3;
    bm = xcd * LX + (j % LX);
    bn = j / LX;
    if (bm >= NBM) return;
  }

  __shared__ __align__(16) short As[128 * 32];
  __shared__ __align__(16) short Bs[128 * 32];
  const int tid = threadIdx.x;
  const int lane = tid & 63, wave = tid >> 6;
  const int wr = wave >> 1, wc = wave & 1;

  floatx4 acc[4][4];
#pragma unroll
  for (int i = 0; i < 4; ++i)
#pragma unroll
    for (int j2 = 0; j2 < 4; ++j2) acc[i][j2] = (floatx4){0.f, 0.f, 0.f, 0.f};

  const int sr = tid >> 2;
  const int sc = (tid & 3) * 8;
  const unsigned short* Ab = A + (size_t)((MOFF + bm) * 128 + sr) * K + sc;
  const unsigned short* Bb = Bw + (size_t)(bn * 128 + sr) * K + sc;
  const size_t rowK64 = (size_t)64 * K;

  const int fr = lane & 15;
  const int fk = (lane >> 4) * 8;
  const int aoff0 = (wr * 64 + fr) * 32 + fk;
  const int boff0 = (wc * 64 + fr) * 32 + fk;

  for (int k0 = 0; k0 < K; k0 += 32) {
    __syncthreads();  // previous compute done before overwrite
    __builtin_amdgcn_global_load_lds(GAS(Ab + k0),          LAS(As + tid * 8), 16, 0, 0);
    __builtin_amdgcn_global_load_lds(GAS(Ab + rowK64 + k0), LAS(As + 2048 + tid * 8), 16, 0, 0);
    __builtin_amdgcn_global_load_lds(GAS(Bb + k0),          LAS(Bs + tid * 8), 16, 0, 0);
    __builtin_amdgcn_global_load_lds(GAS(Bb + rowK64 + k0), LAS(Bs + 2048 + tid * 8), 16, 0, 0);
    __syncthreads();  // drains vmcnt -> LDS ready

    short8 af[4], bf[4];
#pragma unroll
    for (int mt = 0; mt < 4; ++mt) af[mt] = *(const short8*)&As[aoff0 + mt * 16 * 32];
#pragma unroll
    for (int nt = 0; nt < 4; ++nt) bf[nt] = *(const short8*)&Bs[boff0 + nt * 16 * 32];
#pragma unroll
    for (int mt = 0; mt < 4; ++mt)
#pragma unroll
      for (int nt = 0; nt < 4; ++nt)
        acc[mt][nt] = __builtin_amdgcn_mfma_f32_16x16x32_bf16(af[mt], bf[nt], acc[mt][nt], 0, 0, 0);
  }

  const int er = (lane >> 4) * 4, ec = lane & 15;
#pragma unroll
  for (int mt = 0; mt < 4; ++mt) {
#pragma unroll
    for (int nt = 0; nt < 4; ++nt) {
#pragma unroll
      for (int i = 0; i < 4; ++i) {
        int r = (MOFF + bm) * 128 + wr * 64 + mt * 16 + er + i;
        int c = bn * 128 + wc * 64 + nt * 16 + ec;
        float v = acc[mt][nt][i];
        if constexpr (MODE == 0) {
          int bb = r >> 11, t = r & 2047;
          ((unsigned short*)Cout)[((size_t)bb * LPAD + 3 + t) * DIM + c] = f2bf(v + bias[c]);
        } else if constexpr (MODE == 1) {
          if (r < M2 && c < 48) ((float*)Cout)[(size_t)r * 48 + c] = v;
        } else {
          if (r < M2) ((float*)Cout)[(size_t)r * DMODEL + c] = v + bias[c];
        }
      }
    }
  }
}

// ---------------- delta precompute: softplus(d_raw @ W_dt.T + b_dt) -> bf16 ----------------
__global__ __launch_bounds__(256) void delta_kernel(const float* __restrict__ xdbl,
                                                    const float* __restrict__ W_dt,
                                                    const float* __restrict__ b_dt,
                                                    unsigned short* __restrict__ delta) {
  const int d = blockIdx.y * 256 + threadIdx.x;
  const int r0 = blockIdx.x * 8;
  float wv[16];
  const float4* wp = (const float4*)(W_dt + (size_t)d * 16);
#pragma unroll
  for (int q = 0; q < 4; ++q) {
    float4 t = wp[q];
    wv[q * 4 + 0] = t.x; wv[q * 4 + 1] = t.y; wv[q * 4 + 2] = t.z; wv[q * 4 + 3] = t.w;
  }
  const float bd = b_dt[d];
#pragma unroll
  for (int j = 0; j < 8; ++j) {
    const float* dr = xdbl + (size_t)(r0 + j) * 48;   // uniform -> s_load
    float z0 = bd, z1 = 0.f, z2 = 0.f, z3 = 0.f;
#pragma unroll
    for (int n = 0; n < 16; n += 4) {
      z0 = fmaf(dr[n + 0], wv[n + 0], z0);
      z1 = fmaf(dr[n + 1], wv[n + 1], z1);
      z2 = fmaf(dr[n + 2], wv[n + 2], z2);
      z3 = fmaf(dr[n + 3], wv[n + 3], z3);
    }
    float z = (z0 + z1) + (z2 + z3);
    float dl = (z > 20.f) ? z : __logf(1.f + __expf(z));
    delta[(size_t)(r0 + j) * DIM + d] = f2bf(dl);
  }
}

// ---------------- chunked scan, pass 1: per-chunk (sumd, q) -> bf16 ----------------
__global__ __launch_bounds__(256) void scan_pass1(const unsigned short* __restrict__ xc,
                                                  const unsigned short* __restrict__ dl,
                                                  const float* __restrict__ xd,
                                                  unsigned short* __restrict__ sdbuf,
                                                  unsigned short* __restrict__ qbuf) {
  const int wid = __builtin_amdgcn_readfirstlane((int)(threadIdx.x >> 6));
  const int lane = threadIdx.x & 63;
  const int W = blockIdx.x * 4 + wid;
  const int dg = W & 31;
  const int rest = W >> 5;
  const int c = rest % NCH;
  const int b = rest / NCH;
  const int d = dg * 64 + lane;
  const int t0 = c * CS;
  const int nst = (t0 + CS <= LC) ? CS : (LC - t0);

  float2v A2L[8];
#pragma unroll
  for (int i = 0; i < 8; ++i)
    A2L[i] = (float2v){AeT[2 * i] * LOG2E, AeT[2 * i + 1] * LOG2E};

  float2v h2[8];
#pragma unroll
  for (int i = 0; i < 8; ++i) h2[i] = (float2v){0.f, 0.f};
  float sumd = 0.f;

  const size_t row0 = (size_t)b * LC + t0;
  const float* xdb = xd + row0 * 48 + 16;            // B cols (uniform -> s_load)
  const unsigned short* xcp = xc + row0 * DIM + d;
  const unsigned short* dp  = dl + row0 * DIM + d;

  float2v BA[8], BB[8];
#pragma unroll
  for (int j = 0; j < 8; ++j) BA[j] = *(const float2v*)(xdb + 2 * j);
  float d0v = bf2f(dp[0]), x0v = bf2f(xcp[0]);

  auto step = [&](const float2v (&Bv)[8], float dlt, float xcv) {
    sumd += dlt;
    float2v dlt2 = (float2v){dlt, dlt};
    float2v xcv2 = (float2v){xcv, xcv};
#pragma unroll
    for (int i = 0; i < 8; ++i) {
      float2v arg = pk_mul_vv(dlt2, A2L[i]);
      float e0 = exp2_raw(arg.x), e1 = exp2_raw(arg.y);
      float2v e2 = (float2v){e0, e1};
      h2[i] = pk_fma_vvv(h2[i], e2, pk_mul_sv(Bv[i], xcv2));
    }
  };

  for (int s = 0; s < nst; s += 2) {
    int s1 = (s + 1 < nst) ? s + 1 : s;
#pragma unroll
    for (int j = 0; j < 8; ++j) BB[j] = *(const float2v*)(xdb + (size_t)s1 * 48 + 2 * j);
    float d1v = bf2f(dp[(size_t)s1 * DIM]);
    float x1v = bf2f(xcp[(size_t)s1 * DIM]);
    step(BA, d0v, x0v);
    if (s + 1 >= nst) break;
    int s2 = (s + 2 < nst) ? s + 2 : s + 1;
#pragma unroll
    for (int j = 0; j < 8; ++j) BA[j] = *(const float2v*)(xdb + (size_t)s2 * 48 + 2 * j);
    d0v = bf2f(dp[(size_t)s2 * DIM]);
    x0v = bf2f(xcp[(size_t)s2 * DIM]);
    step(BB, d1v, x1v);
  }

  sdbuf[((size_t)(b * NCH + c) << 11) + d] = f2bf(sumd);
  const size_t base = ((size_t)(b * NCH + c) * 16) * 2048 + d;
#pragma unroll
  for (int i = 0; i < 8; ++i) {
    qbuf[base + ((size_t)(2 * i) << 11)]     = f2bf(h2[i].x);
    qbuf[base + ((size_t)(2 * i + 1) << 11)] = f2bf(h2[i].y);
  }
}

// ---------------- boundary scan: h across chunks; writes h_init over q ----------------
__global__ __launch_bounds__(64) void scan_boundary(const unsigned short* __restrict__ sdbuf,
                                                    unsigned short* __restrict__ qbuf) {
  const int d = blockIdx.x * 64 + threadIdx.x;
  const int b = blockIdx.y;
  float h[16];
#pragma unroll
  for (int n = 0; n < 16; ++n) h[n] = 0.f;
  for (int c = 0; c < NCH; ++c) {
    const float sd = bf2f(sdbuf[((size_t)(b * NCH + c) << 11) + d]);
    const size_t base = ((size_t)(b * NCH + c) * 16) * 2048 + d;
    float qv[16];
#pragma unroll
    for (int n = 0; n < 16; ++n) qv[n] = bf2f(qbuf[base + ((size_t)n << 11)]);
#pragma unroll
    for (int n = 0; n < 16; ++n) {
      float Pv = __expf(sd * AeT[n]);
      qbuf[base + ((size_t)n << 11)] = f2bf(h[n]);   // h at chunk start
      h[n] = fmaf(Pv, h[n], qv[n]);
    }
  }
}

// ---------------- chunked scan, pass 2: recompute with h_init, emit y ----------------
// NOTE: y aliases dl (in-place, same [r][d] layout); per-element load precedes store
// within the owning thread, and no two threads touch the same element.
__global__ __launch_bounds__(256) void scan_pass2(const unsigned short* __restrict__ xc,
                                                  const unsigned short* __restrict__ dl,
                                                  const float* __restrict__ xd,
                                                  const unsigned short* __restrict__ hinit,
                                                  unsigned short* __restrict__ y) {
  const int wid = __builtin_amdgcn_readfirstlane((int)(threadIdx.x >> 6));
  const int lane = threadIdx.x & 63;
  const int W = blockIdx.x * 4 + wid;
  const int dg = W & 31;
  const int rest = W >> 5;
  const int c = rest % NCH;
  const int b = rest / NCH;
  const int d = dg * 64 + lane;
  const int t0 = c * CS;
  const int nst = (t0 + CS <= LC) ? CS : (LC - t0);

  float2v A2L[8];
#pragma unroll
  for (int i = 0; i < 8; ++i)
    A2L[i] = (float2v){AeT[2 * i] * LOG2E, AeT[2 * i + 1] * LOG2E};

  const size_t base = ((size_t)(b * NCH + c) * 16) * 2048 + d;
  float2v h2[8];
#pragma unroll
  for (int i = 0; i < 8; ++i)
    h2[i] = (float2v){bf2f(hinit[base + ((size_t)(2 * i) << 11)]),
                      bf2f(hinit[base + ((size_t)(2 * i + 1) << 11)])};

  const size_t row0 = (size_t)b * LC + t0;
  const float* xdb = xd + row0 * 48 + 16;            // B at [j], C at [16+j]
  const unsigned short* xcp = xc + row0 * DIM + d;
  const unsigned short* dp  = dl + row0 * DIM + d;
  unsigned short* yp = y + row0 * DIM + d;

  float2v BA[8], CA[8], BB[8], CB[8];
#pragma unroll
  for (int j = 0; j < 8; ++j) {
    BA[j] = *(const float2v*)(xdb + 2 * j);
    CA[j] = *(const float2v*)(xdb + 16 + 2 * j);
  }
  float d0v = bf2f(dp[0]), x0v = bf2f(xcp[0]);

  auto step = [&](const float2v (&Bv)[8], const float2v (&Cv)[8], float dlt, float xcv, int s) {
    float2v dlt2 = (float2v){dlt, dlt};
    float2v xcv2 = (float2v){xcv, xcv};
    float2v y2[4];
#pragma unroll
    for (int i = 0; i < 4; ++i) y2[i] = (float2v){0.f, 0.f};
#pragma unroll
    for (int i = 0; i < 8; ++i) {
      float2v arg = pk_mul_vv(dlt2, A2L[i]);
      float e0 = exp2_raw(arg.x), e1 = exp2_raw(arg.y);
      float2v e2 = (float2v){e0, e1};
      h2[i] = pk_fma_vvv(h2[i], e2, pk_mul_sv(Bv[i], xcv2));
      y2[i & 3] = pk_fma_vsv(h2[i], Cv[i], y2[i & 3]);
    }
    float2v s01 = pk_add_vv(y2[0], y2[1]);
    float2v s23 = pk_add_vv(y2[2], y2[3]);
    float2v st = pk_add_vv(s01, s23);
    yp[(size_t)s * DIM] = f2bf(st.x + st.y);
  };

  for (int s = 0; s < nst; s += 2) {
    int s1 = (s + 1 < nst) ? s + 1 : s;
#pragma unroll
    for (int j = 0; j < 8; ++j) {
      BB[j] = *(const float2v*)(xdb + (size_t)s1 * 48 + 2 * j);
      CB[j] = *(const float2v*)(xdb + (size_t)s1 * 48 + 16 + 2 * j);
    }
    float d1v = bf2f(dp[(size_t)s1 * DIM]);
    float x1v = bf2f(xcp[(size_t)s1 * DIM]);
    step(BA, CA, d0v, x0v, s);
    if (s + 1 >= nst) break;
    int s2 = (s + 2 < nst) ? s + 2 : s + 1;
#pragma unroll
    for (int j = 0; j < 8; ++j) {
      BA[j] = *(const float2v*)(xdb + (size_t)s2 * 48 + 2 * j);
      CA[j] = *(const float2v*)(xdb + (size_t)s2 * 48 + 16 + 2 * j);
    }
    d0v = bf2f(dp[(size_t)s2 * DIM]);
    x0v = bf2f(xcp[(size_t)s2 * DIM]);
    step(BB, CB, d1v, x1v, s + 1);
  }
}

// ---------------- launch ----------------
extern "C" void kernel_launch(void* const* d_in, const int* in_sizes, int n_in,
                              void* d_out, int out_size, void* d_ws, size_t ws_size,
                              hipStream_t stream) {
  const float* x      = (const float*)d_in[0];
  const float* W_in   = (const float*)d_in[1];
  const float* b_in   = (const float*)d_in[2];
  const float* conv_w = (const float*)d_in[3];
  const float* conv_b = (const float*)d_in[4];
  const float* W_x    = (const float*)d_in[5];
  const float* W_dt   = (const float*)d_in[6];
  const float* b_dt   = (const float*)d_in[7];
  const float* W_out  = (const float*)d_in[8];
  const float* b_out  = (const float*)d_in[9];

  char* w = (char*)d_ws;
  // region 0 (67.63 MB): xp (LPAD layout) -> delta [M2P][DIM] -> y (in-place over delta)
  unsigned short* xp    = (unsigned short*)w;
  unsigned short* delta = (unsigned short*)w;
  unsigned short* ybuf  = (unsigned short*)w;
  size_t off = (size_t)M2P * DIM * 2;                                  // 67,633,152
  unsigned short* xcb  = (unsigned short*)(w + off); off += (size_t)M2P * DIM * 2;
  size_t xA_off = off;                                                 // 135,266,304
  unsigned short* xA   = (unsigned short*)(w + off); off += (size_t)16384 * 1024 * 2;
  unsigned short* wInB = (unsigned short*)(w + off); off += (size_t)2048 * 1024 * 2;
  unsigned short* wOutB= (unsigned short*)(w + off); off += (size_t)1024 * 2048 * 2;
  unsigned short* wXB  = (unsigned short*)(w + off); off += (size_t)128 * 2048 * 2;
  float* xdbl          = (float*)(w + off);          off += (size_t)M2 * 48 * 4;
  // sdbuf (2.13 MB bf16) + qbuf (34.08 MB bf16) reuse xA+wInB region (dead after gemm1)
  unsigned short* sdbuf = (unsigned short*)(w + xA_off);
  unsigned short* qbuf  = (unsigned short*)(w + xA_off + (size_t)B8 * NCH * 2048 * 2);
  (void)ws_size; (void)in_sizes; (void)n_in; (void)out_size;

  cvt_f32_bf16<<<8192, 256, 0, stream>>>(x, xA, 2097152);
  cvt_f32_bf16<<<1024, 256, 0, stream>>>(W_in, wInB, 262144);
  cvt_f32_bf16<<<1024, 256, 0, stream>>>(W_out, wOutB, 262144);
  cvt_f32_bf16<<<48,   256, 0, stream>>>(W_x, wXB, 12288);
  zero_pads<<<48, 256, 0, stream>>>(xp);

  // gemm<0>: M=16384 (128 tiles, perfectly balanced: 8 blocks/CU)
  gemm_bt<0, 128, 16, 16, 0, 0><<<2048, 256, 0, stream>>>(xA, wInB, b_in, xp, 1024);
  conv_kernel<<<dim3(LC, B8), 256, 0, stream>>>(xp, conv_w, conv_b, xcb);
  // gemm<1>: main 128 tiles balanced + 1-tile tail (rows 16384..16511, masked)
  gemm_bt<1, 128, 1, 16, 0, 0><<<128, 256, 0, stream>>>(xcb, wXB, nullptr, xdbl, 2048);
  gemm_bt<1, 1, 1, 1, 128, 1><<<1, 256, 0, stream>>>(xcb, wXB, nullptr, xdbl, 2048);
  delta_kernel<<<dim3(2051, 8), 256, 0, stream>>>(xdbl, W_dt, b_dt, delta);

  scan_pass1<<<4160, 256, 0, stream>>>(xcb, delta, xdbl, sdbuf, qbuf);
  scan_boundary<<<dim3(32, B8), 64, 0, stream>>>(sdbuf, qbuf);
  scan_pass2<<<4160, 256, 0, stream>>>(xcb, delta, xdbl, qbuf, ybuf);

  // gemm<2>: main 128 tiles balanced (4 blocks/CU exact) + 1-tile tail (masked r<M2)
  gemm_bt<2, 128, 8, 16, 0, 0><<<1024, 256, 0, stream>>>(ybuf, wOutB, b_out, (float*)d_out, 2048);
  gemm_bt<2, 1, 8, 1, 128, 1><<<8, 256, 0, stream>>>(ybuf, wOutB, b_out, (float*)d_out, 2048);
}

// Round 9
// 579.567 us; speedup vs baseline: 1.2042x; 1.2042x over previous
//
#include <hip/hip_runtime.h>
#include <cstdint>
#include <cstddef>

#define B8 8
#define LSEQ 2048
#define LC 2051
#define DMODEL 1024
#define DIM 2048
#define LPAD 2054           // 3 + 2048 + 3 zero-padded rows per batch
#define M2 16408            // B8*LC valid rows
#define M2P 16512           // padded to multiple of 128
#define CS 32               // scan chunk size
#define NCH 65              // ceil(2051/32)

typedef __attribute__((ext_vector_type(8))) short short8;
typedef __attribute__((ext_vector_type(4))) float floatx4;
typedef __attribute__((ext_vector_type(2))) float float2v;

// A_n = -exp(-n/3), n=0..15
__device__ __constant__ float AeT[16] = {
  -1.0f,          -0.71653131f, -0.51341712f, -0.36787944f,
  -0.26359714f,   -0.18887560f, -0.13533528f, -0.09697208f,
  -0.06948345f,   -0.04978707f, -0.03567399f, -0.02556154f,
  -0.01831564f,   -0.01312373f, -0.00940356f, -0.00673795f};

#define LOG2E 1.44269504088896f

__device__ __forceinline__ float bf2f(unsigned short h) {
  union { unsigned int u; float f; } v; v.u = ((unsigned int)h) << 16; return v.f;
}
__device__ __forceinline__ unsigned short f2bf(float f) {
  union { float f; unsigned int u; } v; v.f = f;
  unsigned int r = (v.u + 0x7FFFu + ((v.u >> 16) & 1u)) >> 16;
  return (unsigned short)r;
}

// ---- packed fp32 helpers (VOP3P). One scalar operand allowed per instr. ----
__device__ __forceinline__ float2v pk_mul_vv(float2v a, float2v b) {
  float2v d; asm("v_pk_mul_f32 %0, %1, %2" : "=v"(d) : "v"(a), "v"(b)); return d;
}
__device__ __forceinline__ float2v pk_mul_sv(float2v bs, float2v a) {   // bs wave-uniform (SGPR)
  float2v d; asm("v_pk_mul_f32 %0, %1, %2" : "=v"(d) : "s"(bs), "v"(a)); return d;
}
__device__ __forceinline__ float2v pk_fma_vvv(float2v a, float2v b, float2v c) {
  float2v d; asm("v_pk_fma_f32 %0, %1, %2, %3" : "=v"(d) : "v"(a), "v"(b), "v"(c)); return d;
}
__device__ __forceinline__ float2v pk_fma_vsv(float2v a, float2v bs, float2v c) { // bs uniform
  float2v d; asm("v_pk_fma_f32 %0, %1, %2, %3" : "=v"(d) : "v"(a), "s"(bs), "v"(c)); return d;
}
__device__ __forceinline__ float2v pk_add_vv(float2v a, float2v b) {
  float2v d; asm("v_pk_add_f32 %0, %1, %2" : "=v"(d) : "v"(a), "v"(b)); return d;
}
__device__ __forceinline__ float exp2_raw(float x) {   // 2^x
  float d; asm("v_exp_f32 %0, %1" : "=v"(d) : "v"(x)); return d;
}

// ---------------- fp32 -> bf16 convert (8 elems/thread) ----------------
__global__ __launch_bounds__(256) void cvt_f32_bf16(const float* __restrict__ in,
                                                    unsigned short* __restrict__ out,
                                                    int n8) {
  int i = blockIdx.x * 256 + threadIdx.x;
  if (i >= n8) return;
  const float4* p = (const float4*)in + (size_t)i * 2;
  float4 a = p[0], b = p[1];
  uint4 o;
  o.x = (unsigned)f2bf(a.x) | ((unsigned)f2bf(a.y) << 16);
  o.y = (unsigned)f2bf(a.z) | ((unsigned)f2bf(a.w) << 16);
  o.z = (unsigned)f2bf(b.x) | ((unsigned)f2bf(b.y) << 16);
  o.w = (unsigned)f2bf(b.z) | ((unsigned)f2bf(b.w) << 16);
  *((uint4*)out + i) = o;
}

// ---------------- zero the 6 pad rows per batch of xp ----------------
__global__ __launch_bounds__(256) void zero_pads(unsigned short* __restrict__ xp) {
  int i = blockIdx.x * 256 + threadIdx.x;      // 0..12287
  int b = i / 1536;
  int r6 = (i % 1536) / 256;
  int dd = (i % 256) * 8;
  int row = (r6 < 3) ? r6 : (2048 + r6);       // 0,1,2,2051,2052,2053
  uint4 z = make_uint4(0, 0, 0, 0);
  *(uint4*)(xp + ((size_t)b * LPAD + row) * DIM + dd) = z;
}

// ---------------- depthwise conv1d: xp(padded bf16) -> xc bf16 ----------------
__global__ __launch_bounds__(256) void conv_kernel(const unsigned short* __restrict__ xp,
                                                   const float* __restrict__ conv_w,
                                                   const float* __restrict__ conv_b,
                                                   unsigned short* __restrict__ xc) {
  const int tc = blockIdx.x, b = blockIdx.y;
  const int d0 = threadIdx.x * 8;
  const unsigned short* base = xp + ((size_t)b * LPAD + tc) * DIM + d0;

  float4 cw[8];
#pragma unroll
  for (int j = 0; j < 8; ++j) cw[j] = *(const float4*)(conv_w + (size_t)(d0 + j) * 4);

  float acc[8];
  const float4* cb4 = (const float4*)(conv_b + d0);
  float4 cb0 = cb4[0], cb1 = cb4[1];
  acc[0] = cb0.x; acc[1] = cb0.y; acc[2] = cb0.z; acc[3] = cb0.w;
  acc[4] = cb1.x; acc[5] = cb1.y; acc[6] = cb1.z; acc[7] = cb1.w;

#pragma unroll
  for (int k = 0; k < 4; ++k) {
    uint4 v = *(const uint4*)(base + (size_t)k * DIM);
    unsigned short e[8];
    e[0] = v.x & 0xffff; e[1] = v.x >> 16; e[2] = v.y & 0xffff; e[3] = v.y >> 16;
    e[4] = v.z & 0xffff; e[5] = v.z >> 16; e[6] = v.w & 0xffff; e[7] = v.w >> 16;
#pragma unroll
    for (int j = 0; j < 8; ++j)
      acc[j] = fmaf(bf2f(e[j]), ((const float*)&cw[j])[k], acc[j]);
  }
  uint4 o;
  o.x = (unsigned)f2bf(acc[0]) | ((unsigned)f2bf(acc[1]) << 16);
  o.y = (unsigned)f2bf(acc[2]) | ((unsigned)f2bf(acc[3]) << 16);
  o.z = (unsigned)f2bf(acc[4]) | ((unsigned)f2bf(acc[5]) << 16);
  o.w = (unsigned)f2bf(acc[6]) | ((unsigned)f2bf(acc[7]) << 16);
  *(uint4*)(xc + ((size_t)b * LC + tc) * DIM + d0) = o;
}

#define GAS(p) ((const __attribute__((address_space(1))) void*)(p))
#define LAS(p) ((__attribute__((address_space(3))) void*)(p))

// ---------------- bf16 MFMA GEMM, m97 structure with BK=64 ----------------
// C = A(MxK) @ B(NxK)^T. 128x128 tile, 4 waves, BK=64 (half the barrier drains of BK=32).
// LDS tiles [128 rows][64 cols] bf16 = 16KB each, XOR-swizzled in 16B blocks:
//   phys_blk = log_blk ^ (row&7)  (8 blocks/row) -> frag ds_read_b128 is 2-way (free).
// Swizzle applied BOTH sides (rule #21): inverse on global staging source (linear LDS
// dest for global_load_lds) and forward on read offsets. row&7 == (tid>>3)&7 == fr&7.
// XCD-banded 1D remap: bm = (gid&7)*LX + j%LX, bn = j/LX; grid = 8*LX*NBN.
// MODE 0: gemm1 -> xp padded bf16, +b_in; MODE 1: xdbl fp32 [M2][48]; MODE 2: out fp32 +b_out.
template <int MODE, int NBM, int NBN, int LX>
__global__ __launch_bounds__(256) void gemm_bt(const unsigned short* __restrict__ A,
                                               const unsigned short* __restrict__ Bw,
                                               const float* __restrict__ bias,
                                               void* __restrict__ Cout, int K) {
  const int gid = blockIdx.x;
  const int xcd = gid & 7;
  const int j = gid >> 3;
  const int bm = xcd * LX + (j % LX);
  const int bn = j / LX;
  if (bm >= NBM) return;

  __shared__ __align__(16) unsigned short As[128 * 64];   // 16KB
  __shared__ __align__(16) unsigned short Bs[128 * 64];   // 16KB
  const int tid = threadIdx.x;
  const int lane = tid & 63, wave = tid >> 6;
  const int wr = wave >> 1, wc = wave & 1;

  floatx4 acc[4][4];
#pragma unroll
  for (int i = 0; i < 4; ++i)
#pragma unroll
    for (int j2 = 0; j2 < 4; ++j2) acc[i][j2] = (floatx4){0.f, 0.f, 0.f, 0.f};

  // staging: load L in 0..3 covers line = L*256+tid; row = line>>3 = L*32 + (tid>>3),
  // phys_blk = line&7 = tid&7, logical blk = phys ^ (row&7) = (tid&7)^((tid>>3)&7).
  const int srow = tid >> 3;                       // 0..31 (+ L*32)
  const int scol = ((tid & 7) ^ ((tid >> 3) & 7)) * 8;
  const unsigned short* Ab[4];
  const unsigned short* Bb[4];
#pragma unroll
  for (int L = 0; L < 4; ++L) {
    Ab[L] = A  + (size_t)(bm * 128 + L * 32 + srow) * K + scol;
    Bb[L] = Bw + (size_t)(bn * 128 + L * 32 + srow) * K + scol;
  }

  // fragment read offsets: row = (half)*64 + m*16 + fr; elem blk = kk*4 + hi, phys = blk^(fr&7)
  const int fr = lane & 15;
  const int hi = lane >> 4;
  const int fx = fr & 7;

  for (int k0 = 0; k0 < K; k0 += 64) {
    __syncthreads();  // previous compute done before overwrite
#pragma unroll
    for (int L = 0; L < 4; ++L) {
      __builtin_amdgcn_global_load_lds(GAS(Ab[L] + k0), LAS(As + L * 2048 + tid * 8), 16, 0, 0);
      __builtin_amdgcn_global_load_lds(GAS(Bb[L] + k0), LAS(Bs + L * 2048 + tid * 8), 16, 0, 0);
    }
    __syncthreads();  // drains vmcnt -> LDS ready

#pragma unroll
    for (int kk = 0; kk < 2; ++kk) {
      const int pb = ((kk * 4 + hi) ^ fx) * 8;
      short8 af[4], bf[4];
#pragma unroll
      for (int mt = 0; mt < 4; ++mt) af[mt] = *(const short8*)&As[(wr * 64 + mt * 16 + fr) * 64 + pb];
#pragma unroll
      for (int nt = 0; nt < 4; ++nt) bf[nt] = *(const short8*)&Bs[(wc * 64 + nt * 16 + fr) * 64 + pb];
#pragma unroll
      for (int mt = 0; mt < 4; ++mt)
#pragma unroll
        for (int nt = 0; nt < 4; ++nt)
          acc[mt][nt] = __builtin_amdgcn_mfma_f32_16x16x32_bf16(af[mt], bf[nt], acc[mt][nt], 0, 0, 0);
    }
  }

  const int er = (lane >> 4) * 4, ec = lane & 15;
#pragma unroll
  for (int mt = 0; mt < 4; ++mt) {
#pragma unroll
    for (int nt = 0; nt < 4; ++nt) {
#pragma unroll
      for (int i = 0; i < 4; ++i) {
        int r = bm * 128 + wr * 64 + mt * 16 + er + i;
        int c = bn * 128 + wc * 64 + nt * 16 + ec;
        float v = acc[mt][nt][i];
        if constexpr (MODE == 0) {
          int bb = r >> 11, t = r & 2047;
          ((unsigned short*)Cout)[((size_t)bb * LPAD + 3 + t) * DIM + c] = f2bf(v + bias[c]);
        } else if constexpr (MODE == 1) {
          if (r < M2 && c < 48) ((float*)Cout)[(size_t)r * 48 + c] = v;
        } else {
          if (r < M2) ((float*)Cout)[(size_t)r * DMODEL + c] = v + bias[c];
        }
      }
    }
  }
}

// ---------------- delta precompute: softplus(d_raw @ W_dt.T + b_dt) -> bf16 ----------------
__global__ __launch_bounds__(256) void delta_kernel(const float* __restrict__ xdbl,
                                                    const float* __restrict__ W_dt,
                                                    const float* __restrict__ b_dt,
                                                    unsigned short* __restrict__ delta) {
  const int d = blockIdx.y * 256 + threadIdx.x;
  const int r0 = blockIdx.x * 8;
  float wv[16];
  const float4* wp = (const float4*)(W_dt + (size_t)d * 16);
#pragma unroll
  for (int q = 0; q < 4; ++q) {
    float4 t = wp[q];
    wv[q * 4 + 0] = t.x; wv[q * 4 + 1] = t.y; wv[q * 4 + 2] = t.z; wv[q * 4 + 3] = t.w;
  }
  const float bd = b_dt[d];
#pragma unroll
  for (int j = 0; j < 8; ++j) {
    const float* dr = xdbl + (size_t)(r0 + j) * 48;   // uniform -> s_load
    float z0 = bd, z1 = 0.f, z2 = 0.f, z3 = 0.f;
#pragma unroll
    for (int n = 0; n < 16; n += 4) {
      z0 = fmaf(dr[n + 0], wv[n + 0], z0);
      z1 = fmaf(dr[n + 1], wv[n + 1], z1);
      z2 = fmaf(dr[n + 2], wv[n + 2], z2);
      z3 = fmaf(dr[n + 3], wv[n + 3], z3);
    }
    float z = (z0 + z1) + (z2 + z3);
    float dl = (z > 20.f) ? z : __logf(1.f + __expf(z));
    delta[(size_t)(r0 + j) * DIM + d] = f2bf(dl);
  }
}

// ---------------- chunked scan, pass 1: per-chunk (sumd, q) -> bf16 ----------------
__global__ __launch_bounds__(256) void scan_pass1(const unsigned short* __restrict__ xc,
                                                  const unsigned short* __restrict__ dl,
                                                  const float* __restrict__ xd,
                                                  unsigned short* __restrict__ sdbuf,
                                                  unsigned short* __restrict__ qbuf) {
  const int wid = __builtin_amdgcn_readfirstlane((int)(threadIdx.x >> 6));
  const int lane = threadIdx.x & 63;
  const int W = blockIdx.x * 4 + wid;
  const int dg = W & 31;
  const int rest = W >> 5;
  const int c = rest % NCH;
  const int b = rest / NCH;
  const int d = dg * 64 + lane;
  const int t0 = c * CS;
  const int nst = (t0 + CS <= LC) ? CS : (LC - t0);

  float2v A2L[8];
#pragma unroll
  for (int i = 0; i < 8; ++i)
    A2L[i] = (float2v){AeT[2 * i] * LOG2E, AeT[2 * i + 1] * LOG2E};

  float2v h2[8];
#pragma unroll
  for (int i = 0; i < 8; ++i) h2[i] = (float2v){0.f, 0.f};
  float sumd = 0.f;

  const size_t row0 = (size_t)b * LC + t0;
  const float* xdb = xd + row0 * 48 + 16;            // B cols (uniform -> s_load)
  const unsigned short* xcp = xc + row0 * DIM + d;
  const unsigned short* dp  = dl + row0 * DIM + d;

  float2v BA[8], BB[8];
#pragma unroll
  for (int j = 0; j < 8; ++j) BA[j] = *(const float2v*)(xdb + 2 * j);
  float d0v = bf2f(dp[0]), x0v = bf2f(xcp[0]);

  auto step = [&](const float2v (&Bv)[8], float dlt, float xcv) {
    sumd += dlt;
    float2v dlt2 = (float2v){dlt, dlt};
    float2v xcv2 = (float2v){xcv, xcv};
#pragma unroll
    for (int i = 0; i < 8; ++i) {
      float2v arg = pk_mul_vv(dlt2, A2L[i]);
      float e0 = exp2_raw(arg.x), e1 = exp2_raw(arg.y);
      float2v e2 = (float2v){e0, e1};
      h2[i] = pk_fma_vvv(h2[i], e2, pk_mul_sv(Bv[i], xcv2));
    }
  };

  for (int s = 0; s < nst; s += 2) {
    int s1 = (s + 1 < nst) ? s + 1 : s;
#pragma unroll
    for (int j = 0; j < 8; ++j) BB[j] = *(const float2v*)(xdb + (size_t)s1 * 48 + 2 * j);
    float d1v = bf2f(dp[(size_t)s1 * DIM]);
    float x1v = bf2f(xcp[(size_t)s1 * DIM]);
    step(BA, d0v, x0v);
    if (s + 1 >= nst) break;
    int s2 = (s + 2 < nst) ? s + 2 : s + 1;
#pragma unroll
    for (int j = 0; j < 8; ++j) BA[j] = *(const float2v*)(xdb + (size_t)s2 * 48 + 2 * j);
    d0v = bf2f(dp[(size_t)s2 * DIM]);
    x0v = bf2f(xcp[(size_t)s2 * DIM]);
    step(BB, d1v, x1v);
  }

  sdbuf[((size_t)(b * NCH + c) << 11) + d] = f2bf(sumd);
  const size_t base = ((size_t)(b * NCH + c) * 16) * 2048 + d;
#pragma unroll
  for (int i = 0; i < 8; ++i) {
    qbuf[base + ((size_t)(2 * i) << 11)]     = f2bf(h2[i].x);
    qbuf[base + ((size_t)(2 * i + 1) << 11)] = f2bf(h2[i].y);
  }
}

// ---------------- boundary scan: 1 lane per (b,d,n); h across chunks, h_init over q ----
// 4096 waves (4/SIMD) hide the 65 serial HBM-latency loads (was 256 waves, 1/CU).
__global__ __launch_bounds__(256) void scan_boundary(const unsigned short* __restrict__ sdbuf,
                                                     unsigned short* __restrict__ qbuf) {
  const int tid = threadIdx.x;
  const int n = tid >> 4;                          // 0..15
  const int d = blockIdx.x * 16 + (tid & 15);      // 0..2047
  const int b = blockIdx.y;
  const float aL = AeT[n] * LOG2E;
  float h = 0.f;
  for (int c = 0; c < NCH; ++c) {
    const size_t sbase = ((size_t)(b * NCH + c) << 11);
    const float sd = bf2f(sdbuf[sbase + d]);
    const size_t base = (sbase << 4) + ((size_t)n << 11) + d;
    const float qv = bf2f(qbuf[base]);
    const float Pv = exp2_raw(sd * aL);
    qbuf[base] = f2bf(h);                          // h at chunk start
    h = fmaf(Pv, h, qv);
  }
}

// ---------------- chunked scan, pass 2: recompute with h_init, emit y ----------------
// NOTE: y aliases dl (in-place, same [r][d] layout); per-element load precedes store
// within the owning thread, and no two threads touch the same element.
__global__ __launch_bounds__(256) void scan_pass2(const unsigned short* __restrict__ xc,
                                                  const unsigned short* __restrict__ dl,
                                                  const float* __restrict__ xd,
                                                  const unsigned short* __restrict__ hinit,
                                                  unsigned short* __restrict__ y) {
  const int wid = __builtin_amdgcn_readfirstlane((int)(threadIdx.x >> 6));
  const int lane = threadIdx.x & 63;
  const int W = blockIdx.x * 4 + wid;
  const int dg = W & 31;
  const int rest = W >> 5;
  const int c = rest % NCH;
  const int b = rest / NCH;
  const int d = dg * 64 + lane;
  const int t0 = c * CS;
  const int nst = (t0 + CS <= LC) ? CS : (LC - t0);

  float2v A2L[8];
#pragma unroll
  for (int i = 0; i < 8; ++i)
    A2L[i] = (float2v){AeT[2 * i] * LOG2E, AeT[2 * i + 1] * LOG2E};

  const size_t base = ((size_t)(b * NCH + c) * 16) * 2048 + d;
  float2v h2[8];
#pragma unroll
  for (int i = 0; i < 8; ++i)
    h2[i] = (float2v){bf2f(hinit[base + ((size_t)(2 * i) << 11)]),
                      bf2f(hinit[base + ((size_t)(2 * i + 1) << 11)])};

  const size_t row0 = (size_t)b * LC + t0;
  const float* xdb = xd + row0 * 48 + 16;            // B at [j], C at [16+j]
  const unsigned short* xcp = xc + row0 * DIM + d;
  const unsigned short* dp  = dl + row0 * DIM + d;
  unsigned short* yp = y + row0 * DIM + d;

  float2v BA[8], CA[8], BB[8], CB[8];
#pragma unroll
  for (int j = 0; j < 8; ++j) {
    BA[j] = *(const float2v*)(xdb + 2 * j);
    CA[j] = *(const float2v*)(xdb + 16 + 2 * j);
  }
  float d0v = bf2f(dp[0]), x0v = bf2f(xcp[0]);

  auto step = [&](const float2v (&Bv)[8], const float2v (&Cv)[8], float dlt, float xcv, int s) {
    float2v dlt2 = (float2v){dlt, dlt};
    float2v xcv2 = (float2v){xcv, xcv};
    float2v y2[4];
#pragma unroll
    for (int i = 0; i < 4; ++i) y2[i] = (float2v){0.f, 0.f};
#pragma unroll
    for (int i = 0; i < 8; ++i) {
      float2v arg = pk_mul_vv(dlt2, A2L[i]);
      float e0 = exp2_raw(arg.x), e1 = exp2_raw(arg.y);
      float2v e2 = (float2v){e0, e1};
      h2[i] = pk_fma_vvv(h2[i], e2, pk_mul_sv(Bv[i], xcv2));
      y2[i & 3] = pk_fma_vsv(h2[i], Cv[i], y2[i & 3]);
    }
    float2v s01 = pk_add_vv(y2[0], y2[1]);
    float2v s23 = pk_add_vv(y2[2], y2[3]);
    float2v st = pk_add_vv(s01, s23);
    yp[(size_t)s * DIM] = f2bf(st.x + st.y);
  };

  for (int s = 0; s < nst; s += 2) {
    int s1 = (s + 1 < nst) ? s + 1 : s;
#pragma unroll
    for (int j = 0; j < 8; ++j) {
      BB[j] = *(const float2v*)(xdb + (size_t)s1 * 48 + 2 * j);
      CB[j] = *(const float2v*)(xdb + (size_t)s1 * 48 + 16 + 2 * j);
    }
    float d1v = bf2f(dp[(size_t)s1 * DIM]);
    float x1v = bf2f(xcp[(size_t)s1 * DIM]);
    step(BA, CA, d0v, x0v, s);
    if (s + 1 >= nst) break;
    int s2 = (s + 2 < nst) ? s + 2 : s + 1;
#pragma unroll
    for (int j = 0; j < 8; ++j) {
      BA[j] = *(const float2v*)(xdb + (size_t)s2 * 48 + 2 * j);
      CA[j] = *(const float2v*)(xdb + (size_t)s2 * 48 + 16 + 2 * j);
    }
    d0v = bf2f(dp[(size_t)s2 * DIM]);
    x0v = bf2f(xcp[(size_t)s2 * DIM]);
    step(BB, CB, d1v, x1v, s + 1);
  }
}

// ---------------- launch ----------------
extern "C" void kernel_launch(void* const* d_in, const int* in_sizes, int n_in,
                              void* d_out, int out_size, void* d_ws, size_t ws_size,
                              hipStream_t stream) {
  const float* x      = (const float*)d_in[0];
  const float* W_in   = (const float*)d_in[1];
  const float* b_in   = (const float*)d_in[2];
  const float* conv_w = (const float*)d_in[3];
  const float* conv_b = (const float*)d_in[4];
  const float* W_x    = (const float*)d_in[5];
  const float* W_dt   = (const float*)d_in[6];
  const float* b_dt   = (const float*)d_in[7];
  const float* W_out  = (const float*)d_in[8];
  const float* b_out  = (const float*)d_in[9];

  char* w = (char*)d_ws;
  // region 0 (67.63 MB): xp (LPAD layout) -> delta [M2P][DIM] -> y (in-place over delta)
  unsigned short* xp    = (unsigned short*)w;
  unsigned short* delta = (unsigned short*)w;
  unsigned short* ybuf  = (unsigned short*)w;
  size_t off = (size_t)M2P * DIM * 2;                                  // 67,633,152
  unsigned short* xcb  = (unsigned short*)(w + off); off += (size_t)M2P * DIM * 2;
  size_t xA_off = off;                                                 // 135,266,304
  unsigned short* xA   = (unsigned short*)(w + off); off += (size_t)16384 * 1024 * 2;
  unsigned short* wInB = (unsigned short*)(w + off); off += (size_t)2048 * 1024 * 2;
  unsigned short* wOutB= (unsigned short*)(w + off); off += (size_t)1024 * 2048 * 2;
  unsigned short* wXB  = (unsigned short*)(w + off); off += (size_t)128 * 2048 * 2;
  float* xdbl          = (float*)(w + off);          off += (size_t)M2 * 48 * 4;
  // sdbuf (2.13 MB bf16) + qbuf (34.08 MB bf16) reuse xA+wInB region (dead after gemm1)
  unsigned short* sdbuf = (unsigned short*)(w + xA_off);
  unsigned short* qbuf  = (unsigned short*)(w + xA_off + (size_t)B8 * NCH * 2048 * 2);
  (void)ws_size; (void)in_sizes; (void)n_in; (void)out_size;

  cvt_f32_bf16<<<8192, 256, 0, stream>>>(x, xA, 2097152);
  cvt_f32_bf16<<<1024, 256, 0, stream>>>(W_in, wInB, 262144);
  cvt_f32_bf16<<<1024, 256, 0, stream>>>(W_out, wOutB, 262144);
  cvt_f32_bf16<<<48,   256, 0, stream>>>(W_x, wXB, 12288);
  zero_pads<<<48, 256, 0, stream>>>(xp);

  // single launches, XCD-banded remap (no serial tail kernels)
  gemm_bt<0, 128, 16, 16><<<2048, 256, 0, stream>>>(xA, wInB, b_in, xp, 1024);
  conv_kernel<<<dim3(LC, B8), 256, 0, stream>>>(xp, conv_w, conv_b, xcb);
  gemm_bt<1, 129, 1, 17><<<136, 256, 0, stream>>>(xcb, wXB, nullptr, xdbl, 2048);
  delta_kernel<<<dim3(2051, 8), 256, 0, stream>>>(xdbl, W_dt, b_dt, delta);

  scan_pass1<<<4160, 256, 0, stream>>>(xcb, delta, xdbl, sdbuf, qbuf);
  scan_boundary<<<dim3(128, B8), 256, 0, stream>>>(sdbuf, qbuf);
  scan_pass2<<<4160, 256, 0, stream>>>(xcb, delta, xdbl, qbuf, ybuf);

  gemm_bt<2, 129, 8, 17><<<1088, 256, 0, stream>>>(ybuf, wOutB, b_out, (float*)d_out, 2048);
}

// Round 10
// 537.727 us; speedup vs baseline: 1.2979x; 1.0778x over previous
//
#include <hip/hip_runtime.h>
#include <cstdint>
#include <cstddef>

#define B8 8
#define LSEQ 2048
#define LC 2051
#define DMODEL 1024
#define DIM 2048
#define LPAD 2054           // 3 + 2048 + 3 zero-padded rows per batch
#define M2 16408            // B8*LC valid rows
#define M2P 16512           // padded to multiple of 128
#define CS 32               // scan chunk size
#define NCH 65              // ceil(2051/32)

typedef __attribute__((ext_vector_type(8))) short short8;
typedef __attribute__((ext_vector_type(4))) float floatx4;
typedef __attribute__((ext_vector_type(2))) float float2v;

// A_n = -exp(-n/3), n=0..15
__device__ __constant__ float AeT[16] = {
  -1.0f,          -0.71653131f, -0.51341712f, -0.36787944f,
  -0.26359714f,   -0.18887560f, -0.13533528f, -0.09697208f,
  -0.06948345f,   -0.04978707f, -0.03567399f, -0.02556154f,
  -0.01831564f,   -0.01312373f, -0.00940356f, -0.00673795f};

#define LOG2E 1.44269504088896f

__device__ __forceinline__ float bf2f(unsigned short h) {
  union { unsigned int u; float f; } v; v.u = ((unsigned int)h) << 16; return v.f;
}
__device__ __forceinline__ unsigned short f2bf(float f) {
  union { float f; unsigned int u; } v; v.f = f;
  unsigned int r = (v.u + 0x7FFFu + ((v.u >> 16) & 1u)) >> 16;
  return (unsigned short)r;
}

// ---- packed fp32 helpers (VOP3P). One scalar operand allowed per instr. ----
__device__ __forceinline__ float2v pk_mul_vv(float2v a, float2v b) {
  float2v d; asm("v_pk_mul_f32 %0, %1, %2" : "=v"(d) : "v"(a), "v"(b)); return d;
}
__device__ __forceinline__ float2v pk_mul_sv(float2v bs, float2v a) {   // bs wave-uniform (SGPR)
  float2v d; asm("v_pk_mul_f32 %0, %1, %2" : "=v"(d) : "s"(bs), "v"(a)); return d;
}
__device__ __forceinline__ float2v pk_fma_vvv(float2v a, float2v b, float2v c) {
  float2v d; asm("v_pk_fma_f32 %0, %1, %2, %3" : "=v"(d) : "v"(a), "v"(b), "v"(c)); return d;
}
__device__ __forceinline__ float2v pk_fma_vsv(float2v a, float2v bs, float2v c) { // bs uniform
  float2v d; asm("v_pk_fma_f32 %0, %1, %2, %3" : "=v"(d) : "v"(a), "s"(bs), "v"(c)); return d;
}
__device__ __forceinline__ float2v pk_add_vv(float2v a, float2v b) {
  float2v d; asm("v_pk_add_f32 %0, %1, %2" : "=v"(d) : "v"(a), "v"(b)); return d;
}
__device__ __forceinline__ float exp2_raw(float x) {   // 2^x
  float d; asm("v_exp_f32 %0, %1" : "=v"(d) : "v"(x)); return d;
}

// ---------------- fp32 -> bf16 convert (8 elems/thread) ----------------
__global__ __launch_bounds__(256) void cvt_f32_bf16(const float* __restrict__ in,
                                                    unsigned short* __restrict__ out,
                                                    int n8) {
  int i = blockIdx.x * 256 + threadIdx.x;
  if (i >= n8) return;
  const float4* p = (const float4*)in + (size_t)i * 2;
  float4 a = p[0], b = p[1];
  uint4 o;
  o.x = (unsigned)f2bf(a.x) | ((unsigned)f2bf(a.y) << 16);
  o.y = (unsigned)f2bf(a.z) | ((unsigned)f2bf(a.w) << 16);
  o.z = (unsigned)f2bf(b.x) | ((unsigned)f2bf(b.y) << 16);
  o.w = (unsigned)f2bf(b.z) | ((unsigned)f2bf(b.w) << 16);
  *((uint4*)out + i) = o;
}

// ---------------- zero the 6 pad rows per batch of xp ----------------
__global__ __launch_bounds__(256) void zero_pads(unsigned short* __restrict__ xp) {
  int i = blockIdx.x * 256 + threadIdx.x;      // 0..12287
  int b = i / 1536;
  int r6 = (i % 1536) / 256;
  int dd = (i % 256) * 8;
  int row = (r6 < 3) ? r6 : (2048 + r6);       // 0,1,2,2051,2052,2053
  uint4 z = make_uint4(0, 0, 0, 0);
  *(uint4*)(xp + ((size_t)b * LPAD + row) * DIM + dd) = z;
}

// ---------------- depthwise conv1d, 16 t per block (sliding window) ----------------
// Old version: 1 t/block -> each xp row fetched by 4 blocks on DIFFERENT XCDs (round-robin)
// -> ~4x HBM read amplification. New: 16 t/block reads 19 rows for 16 outputs (1.19x).
// grid (129, 8); reads may run past LPAD rows into region0 tail (allocated, masked outputs).
__global__ __launch_bounds__(256) void conv_kernel(const unsigned short* __restrict__ xp,
                                                   const float* __restrict__ conv_w,
                                                   const float* __restrict__ conv_b,
                                                   unsigned short* __restrict__ xc) {
  const int tc0 = blockIdx.x * 16;
  const int b = blockIdx.y;
  const int d0 = threadIdx.x * 8;

  float4 cw[8];
#pragma unroll
  for (int j = 0; j < 8; ++j) cw[j] = *(const float4*)(conv_w + (size_t)(d0 + j) * 4);
  float cb[8];
  {
    const float4* cb4 = (const float4*)(conv_b + d0);
    float4 c0 = cb4[0], c1 = cb4[1];
    cb[0] = c0.x; cb[1] = c0.y; cb[2] = c0.z; cb[3] = c0.w;
    cb[4] = c1.x; cb[5] = c1.y; cb[6] = c1.z; cb[7] = c1.w;
  }

  const unsigned short* base = xp + ((size_t)b * LPAD + tc0) * DIM + d0;
  unsigned short* outp = xc + ((size_t)b * LC + tc0) * DIM + d0;

  auto loadrow = [&](float (&w)[8], int r) {
    uint4 v = *(const uint4*)(base + (size_t)r * DIM);
    w[0] = bf2f(v.x & 0xffff); w[1] = bf2f(v.x >> 16);
    w[2] = bf2f(v.y & 0xffff); w[3] = bf2f(v.y >> 16);
    w[4] = bf2f(v.z & 0xffff); w[5] = bf2f(v.z >> 16);
    w[6] = bf2f(v.w & 0xffff); w[7] = bf2f(v.w >> 16);
  };

  float wa[8], wb[8], wc[8];
  loadrow(wa, 0); loadrow(wb, 1); loadrow(wc, 2);
#pragma unroll
  for (int i = 0; i < 16; ++i) {
    float wd[8];
    loadrow(wd, i + 3);
    if (tc0 + i < LC) {
      float acc[8];
#pragma unroll
      for (int j = 0; j < 8; ++j) {
        acc[j] = cb[j];
        acc[j] = fmaf(wa[j], cw[j].x, acc[j]);
        acc[j] = fmaf(wb[j], cw[j].y, acc[j]);
        acc[j] = fmaf(wc[j], cw[j].z, acc[j]);
        acc[j] = fmaf(wd[j], cw[j].w, acc[j]);
      }
      uint4 o;
      o.x = (unsigned)f2bf(acc[0]) | ((unsigned)f2bf(acc[1]) << 16);
      o.y = (unsigned)f2bf(acc[2]) | ((unsigned)f2bf(acc[3]) << 16);
      o.z = (unsigned)f2bf(acc[4]) | ((unsigned)f2bf(acc[5]) << 16);
      o.w = (unsigned)f2bf(acc[6]) | ((unsigned)f2bf(acc[7]) << 16);
      *(uint4*)(outp + (size_t)i * DIM) = o;
    }
#pragma unroll
    for (int j = 0; j < 8; ++j) { wa[j] = wb[j]; wb[j] = wc[j]; wc[j] = wd[j]; }
  }
}

#define GAS(p) ((const __attribute__((address_space(1))) void*)(p))
#define LAS(p) ((__attribute__((address_space(3))) void*)(p))

// ---------------- bf16 MFMA GEMM, m97 structure with BK=64 ----------------
// 128x128 tile, 4 waves, BK=64. LDS [128][64] bf16 XOR-swizzled in 16B blocks:
// phys_blk = log_blk ^ (row&7); both-sides (rule #21): inverse on global staging source
// (linear gload_lds dest), forward on read offsets. Bank conflicts: 0 (measured r9).
// Mapping: banded main (bm = (gid&7)*LX + j%LX, bn = j/LX) for gid < 8*LX*NBN;
// TAIL=1 appends blocks gid>=main: bm = 8*LX + e/NBN, bn = e%NBN (same launch, no serial tail).
template <int MODE, int NBM, int NBN, int LX, int TAIL>
__global__ __launch_bounds__(256) void gemm_bt(const unsigned short* __restrict__ A,
                                               const unsigned short* __restrict__ Bw,
                                               const float* __restrict__ bias,
                                               void* __restrict__ Cout, int K) {
  const int gid = blockIdx.x;
  const int mainBlocks = 8 * LX * NBN;
  int bm, bn;
  if (TAIL && gid >= mainBlocks) {
    const int e = gid - mainBlocks;
    bm = 8 * LX + e / NBN;
    bn = e % NBN;
  } else {
    const int xcd = gid & 7;
    const int j = gid >> 3;
    bm = xcd * LX + (j % LX);
    bn = j / LX;
  }
  if (bm >= NBM) return;

  __shared__ __align__(16) unsigned short As[128 * 64];   // 16KB
  __shared__ __align__(16) unsigned short Bs[128 * 64];   // 16KB
  const int tid = threadIdx.x;
  const int lane = tid & 63, wave = tid >> 6;
  const int wr = wave >> 1, wc = wave & 1;

  floatx4 acc[4][4];
#pragma unroll
  for (int i = 0; i < 4; ++i)
#pragma unroll
    for (int j2 = 0; j2 < 4; ++j2) acc[i][j2] = (floatx4){0.f, 0.f, 0.f, 0.f};

  // staging: load L covers line = L*256+tid; row = L*32 + (tid>>3), phys_blk = tid&7,
  // logical blk = phys ^ (row&7) = (tid&7)^((tid>>3)&7).
  const int srow = tid >> 3;
  const int scol = ((tid & 7) ^ ((tid >> 3) & 7)) * 8;
  const unsigned short* Ab[4];
  const unsigned short* Bb[4];
#pragma unroll
  for (int L = 0; L < 4; ++L) {
    Ab[L] = A  + (size_t)(bm * 128 + L * 32 + srow) * K + scol;
    Bb[L] = Bw + (size_t)(bn * 128 + L * 32 + srow) * K + scol;
  }

  const int fr = lane & 15;
  const int hi = lane >> 4;
  const int fx = fr & 7;

  for (int k0 = 0; k0 < K; k0 += 64) {
    __syncthreads();  // previous compute done before overwrite
#pragma unroll
    for (int L = 0; L < 4; ++L) {
      __builtin_amdgcn_global_load_lds(GAS(Ab[L] + k0), LAS(As + L * 2048 + tid * 8), 16, 0, 0);
      __builtin_amdgcn_global_load_lds(GAS(Bb[L] + k0), LAS(Bs + L * 2048 + tid * 8), 16, 0, 0);
    }
    __syncthreads();  // drains vmcnt -> LDS ready

#pragma unroll
    for (int kk = 0; kk < 2; ++kk) {
      const int pb = ((kk * 4 + hi) ^ fx) * 8;
      short8 af[4], bf[4];
#pragma unroll
      for (int mt = 0; mt < 4; ++mt) af[mt] = *(const short8*)&As[(wr * 64 + mt * 16 + fr) * 64 + pb];
#pragma unroll
      for (int nt = 0; nt < 4; ++nt) bf[nt] = *(const short8*)&Bs[(wc * 64 + nt * 16 + fr) * 64 + pb];
#pragma unroll
      for (int mt = 0; mt < 4; ++mt)
#pragma unroll
        for (int nt = 0; nt < 4; ++nt)
          acc[mt][nt] = __builtin_amdgcn_mfma_f32_16x16x32_bf16(af[mt], bf[nt], acc[mt][nt], 0, 0, 0);
    }
  }

  const int er = (lane >> 4) * 4, ec = lane & 15;
#pragma unroll
  for (int mt = 0; mt < 4; ++mt) {
#pragma unroll
    for (int nt = 0; nt < 4; ++nt) {
#pragma unroll
      for (int i = 0; i < 4; ++i) {
        int r = bm * 128 + wr * 64 + mt * 16 + er + i;
        int c = bn * 128 + wc * 64 + nt * 16 + ec;
        float v = acc[mt][nt][i];
        if constexpr (MODE == 0) {
          int bb = r >> 11, t = r & 2047;
          ((unsigned short*)Cout)[((size_t)bb * LPAD + 3 + t) * DIM + c] = f2bf(v + bias[c]);
        } else if constexpr (MODE == 1) {
          if (r < M2 && c < 48) ((float*)Cout)[(size_t)r * 48 + c] = v;
        } else {
          if (r < M2) ((float*)Cout)[(size_t)r * DMODEL + c] = v + bias[c];
        }
      }
    }
  }
}

// ---------------- delta precompute: softplus(d_raw @ W_dt.T + b_dt) -> bf16 ----------------
__global__ __launch_bounds__(256) void delta_kernel(const float* __restrict__ xdbl,
                                                    const float* __restrict__ W_dt,
                                                    const float* __restrict__ b_dt,
                                                    unsigned short* __restrict__ delta) {
  const int d = blockIdx.y * 256 + threadIdx.x;
  const int r0 = blockIdx.x * 8;
  float wv[16];
  const float4* wp = (const float4*)(W_dt + (size_t)d * 16);
#pragma unroll
  for (int q = 0; q < 4; ++q) {
    float4 t = wp[q];
    wv[q * 4 + 0] = t.x; wv[q * 4 + 1] = t.y; wv[q * 4 + 2] = t.z; wv[q * 4 + 3] = t.w;
  }
  const float bd = b_dt[d];
#pragma unroll
  for (int j = 0; j < 8; ++j) {
    const float* dr = xdbl + (size_t)(r0 + j) * 48;   // uniform -> s_load
    float z0 = bd, z1 = 0.f, z2 = 0.f, z3 = 0.f;
#pragma unroll
    for (int n = 0; n < 16; n += 4) {
      z0 = fmaf(dr[n + 0], wv[n + 0], z0);
      z1 = fmaf(dr[n + 1], wv[n + 1], z1);
      z2 = fmaf(dr[n + 2], wv[n + 2], z2);
      z3 = fmaf(dr[n + 3], wv[n + 3], z3);
    }
    float z = (z0 + z1) + (z2 + z3);
    float dl = (z > 20.f) ? z : __logf(1.f + __expf(z));
    delta[(size_t)(r0 + j) * DIM + d] = f2bf(dl);
  }
}

// ---------------- chunked scan, pass 1: per-chunk (sumd, q) -> bf16 ----------------
// Full chunks (nst==CS, 64 of 65) take a fully-unrolled path so the compiler can
// software-pipeline the HBM-latency xc/dl loads (rolled loop had ~1-step distance).
__global__ __launch_bounds__(256) void scan_pass1(const unsigned short* __restrict__ xc,
                                                  const unsigned short* __restrict__ dl,
                                                  const float* __restrict__ xd,
                                                  unsigned short* __restrict__ sdbuf,
                                                  unsigned short* __restrict__ qbuf) {
  const int wid = __builtin_amdgcn_readfirstlane((int)(threadIdx.x >> 6));
  const int lane = threadIdx.x & 63;
  const int W = blockIdx.x * 4 + wid;
  const int dg = W & 31;
  const int rest = W >> 5;
  const int c = rest % NCH;
  const int b = rest / NCH;
  const int d = dg * 64 + lane;
  const int t0 = c * CS;
  const int nst = (t0 + CS <= LC) ? CS : (LC - t0);

  float2v A2L[8];
#pragma unroll
  for (int i = 0; i < 8; ++i)
    A2L[i] = (float2v){AeT[2 * i] * LOG2E, AeT[2 * i + 1] * LOG2E};

  float2v h2[8];
#pragma unroll
  for (int i = 0; i < 8; ++i) h2[i] = (float2v){0.f, 0.f};
  float sumd = 0.f;

  const size_t row0 = (size_t)b * LC + t0;
  const float* xdb = xd + row0 * 48 + 16;            // B cols (uniform -> s_load)
  const unsigned short* xcp = xc + row0 * DIM + d;
  const unsigned short* dp  = dl + row0 * DIM + d;

  auto body = [&](int s) {
    float2v Bv[8];
#pragma unroll
    for (int j = 0; j < 8; ++j) Bv[j] = *(const float2v*)(xdb + (size_t)s * 48 + 2 * j);
    float dlt = bf2f(dp[(size_t)s * DIM]);
    float xcv = bf2f(xcp[(size_t)s * DIM]);
    sumd += dlt;
    float2v dlt2 = (float2v){dlt, dlt};
    float2v xcv2 = (float2v){xcv, xcv};
#pragma unroll
    for (int i = 0; i < 8; ++i) {
      float2v arg = pk_mul_vv(dlt2, A2L[i]);
      float e0 = exp2_raw(arg.x), e1 = exp2_raw(arg.y);
      float2v e2 = (float2v){e0, e1};
      h2[i] = pk_fma_vvv(h2[i], e2, pk_mul_sv(Bv[i], xcv2));
    }
  };

  if (nst == CS) {
#pragma unroll
    for (int s = 0; s < CS; ++s) body(s);
  } else {
    for (int s = 0; s < nst; ++s) body(s);
  }

  sdbuf[((size_t)(b * NCH + c) << 11) + d] = f2bf(sumd);
  const size_t base = ((size_t)(b * NCH + c) * 16) * 2048 + d;
#pragma unroll
  for (int i = 0; i < 8; ++i) {
    qbuf[base + ((size_t)(2 * i) << 11)]     = f2bf(h2[i].x);
    qbuf[base + ((size_t)(2 * i + 1) << 11)] = f2bf(h2[i].y);
  }
}

// ---------------- boundary scan: 1 lane per (b,d,n); h across chunks, h_init over q ----
__global__ __launch_bounds__(256) void scan_boundary(const unsigned short* __restrict__ sdbuf,
                                                     unsigned short* __restrict__ qbuf) {
  const int tid = threadIdx.x;
  const int n = tid >> 4;                          // 0..15
  const int d = blockIdx.x * 16 + (tid & 15);      // 0..2047
  const int b = blockIdx.y;
  const float aL = AeT[n] * LOG2E;
  float h = 0.f;
  for (int c = 0; c < NCH; ++c) {
    const size_t sbase = ((size_t)(b * NCH + c) << 11);
    const float sd = bf2f(sdbuf[sbase + d]);
    const size_t base = (sbase << 4) + ((size_t)n << 11) + d;
    const float qv = bf2f(qbuf[base]);
    const float Pv = exp2_raw(sd * aL);
    qbuf[base] = f2bf(h);                          // h at chunk start
    h = fmaf(Pv, h, qv);
  }
}

// ---------------- chunked scan, pass 2: recompute with h_init, emit y ----------------
// NOTE: y aliases dl (in-place, same [r][d] layout); per-element the only writer is the
// owning thread and it writes row s after reading row s (hoisting dl loads earlier is safe:
// different rows -> different addresses).
__global__ __launch_bounds__(256) void scan_pass2(const unsigned short* __restrict__ xc,
                                                  const unsigned short* __restrict__ dl,
                                                  const float* __restrict__ xd,
                                                  const unsigned short* __restrict__ hinit,
                                                  unsigned short* __restrict__ y) {
  const int wid = __builtin_amdgcn_readfirstlane((int)(threadIdx.x >> 6));
  const int lane = threadIdx.x & 63;
  const int W = blockIdx.x * 4 + wid;
  const int dg = W & 31;
  const int rest = W >> 5;
  const int c = rest % NCH;
  const int b = rest / NCH;
  const int d = dg * 64 + lane;
  const int t0 = c * CS;
  const int nst = (t0 + CS <= LC) ? CS : (LC - t0);

  float2v A2L[8];
#pragma unroll
  for (int i = 0; i < 8; ++i)
    A2L[i] = (float2v){AeT[2 * i] * LOG2E, AeT[2 * i + 1] * LOG2E};

  const size_t base = ((size_t)(b * NCH + c) * 16) * 2048 + d;
  float2v h2[8];
#pragma unroll
  for (int i = 0; i < 8; ++i)
    h2[i] = (float2v){bf2f(hinit[base + ((size_t)(2 * i) << 11)]),
                      bf2f(hinit[base + ((size_t)(2 * i + 1) << 11)])};

  const size_t row0 = (size_t)b * LC + t0;
  const float* xdb = xd + row0 * 48 + 16;            // B at [j], C at [16+j]
  const unsigned short* xcp = xc + row0 * DIM + d;
  const unsigned short* dp  = dl + row0 * DIM + d;
  unsigned short* yp = y + row0 * DIM + d;

  auto body = [&](int s) {
    float2v Bv[8], Cv[8];
#pragma unroll
    for (int j = 0; j < 8; ++j) {
      Bv[j] = *(const float2v*)(xdb + (size_t)s * 48 + 2 * j);
      Cv[j] = *(const float2v*)(xdb + (size_t)s * 48 + 16 + 2 * j);
    }
    float dlt = bf2f(dp[(size_t)s * DIM]);
    float xcv = bf2f(xcp[(size_t)s * DIM]);
    float2v dlt2 = (float2v){dlt, dlt};
    float2v xcv2 = (float2v){xcv, xcv};
    float2v y2[4];
#pragma unroll
    for (int i = 0; i < 4; ++i) y2[i] = (float2v){0.f, 0.f};
#pragma unroll
    for (int i = 0; i < 8; ++i) {
      float2v arg = pk_mul_vv(dlt2, A2L[i]);
      float e0 = exp2_raw(arg.x), e1 = exp2_raw(arg.y);
      float2v e2 = (float2v){e0, e1};
      h2[i] = pk_fma_vvv(h2[i], e2, pk_mul_sv(Bv[i], xcv2));
      y2[i & 3] = pk_fma_vsv(h2[i], Cv[i], y2[i & 3]);
    }
    float2v s01 = pk_add_vv(y2[0], y2[1]);
    float2v s23 = pk_add_vv(y2[2], y2[3]);
    float2v st = pk_add_vv(s01, s23);
    yp[(size_t)s * DIM] = f2bf(st.x + st.y);
  };

  if (nst == CS) {
#pragma unroll
    for (int s = 0; s < CS; ++s) body(s);
  } else {
    for (int s = 0; s < nst; ++s) body(s);
  }
}

// ---------------- launch ----------------
extern "C" void kernel_launch(void* const* d_in, const int* in_sizes, int n_in,
                              void* d_out, int out_size, void* d_ws, size_t ws_size,
                              hipStream_t stream) {
  const float* x      = (const float*)d_in[0];
  const float* W_in   = (const float*)d_in[1];
  const float* b_in   = (const float*)d_in[2];
  const float* conv_w = (const float*)d_in[3];
  const float* conv_b = (const float*)d_in[4];
  const float* W_x    = (const float*)d_in[5];
  const float* W_dt   = (const float*)d_in[6];
  const float* b_dt   = (const float*)d_in[7];
  const float* W_out  = (const float*)d_in[8];
  const float* b_out  = (const float*)d_in[9];

  char* w = (char*)d_ws;
  // region 0 (67.63 MB): xp (LPAD layout) -> delta [M2P][DIM] -> y (in-place over delta)
  unsigned short* xp    = (unsigned short*)w;
  unsigned short* delta = (unsigned short*)w;
  unsigned short* ybuf  = (unsigned short*)w;
  size_t off = (size_t)M2P * DIM * 2;                                  // 67,633,152
  unsigned short* xcb  = (unsigned short*)(w + off); off += (size_t)M2P * DIM * 2;
  size_t xA_off = off;                                                 // 135,266,304
  unsigned short* xA   = (unsigned short*)(w + off); off += (size_t)16384 * 1024 * 2;
  unsigned short* wInB = (unsigned short*)(w + off); off += (size_t)2048 * 1024 * 2;
  unsigned short* wOutB= (unsigned short*)(w + off); off += (size_t)1024 * 2048 * 2;
  unsigned short* wXB  = (unsigned short*)(w + off); off += (size_t)128 * 2048 * 2;
  float* xdbl          = (float*)(w + off);          off += (size_t)M2 * 48 * 4;
  // sdbuf (2.13 MB bf16) + qbuf (34.08 MB bf16) reuse xA+wInB region (dead after gemm1)
  unsigned short* sdbuf = (unsigned short*)(w + xA_off);
  unsigned short* qbuf  = (unsigned short*)(w + xA_off + (size_t)B8 * NCH * 2048 * 2);
  (void)ws_size; (void)in_sizes; (void)n_in; (void)out_size;

  cvt_f32_bf16<<<8192, 256, 0, stream>>>(x, xA, 2097152);
  cvt_f32_bf16<<<1024, 256, 0, stream>>>(W_in, wInB, 262144);
  cvt_f32_bf16<<<1024, 256, 0, stream>>>(W_out, wOutB, 262144);
  cvt_f32_bf16<<<48,   256, 0, stream>>>(W_x, wXB, 12288);
  zero_pads<<<48, 256, 0, stream>>>(xp);

  // gemm<0>: 128 bm tiles exact (8 blocks/CU)
  gemm_bt<0, 128, 16, 16, 0><<<2048, 256, 0, stream>>>(xA, wInB, b_in, xp, 1024);
  conv_kernel<<<dim3(129, B8), 256, 0, stream>>>(xp, conv_w, conv_b, xcb);
  // gemm<1>: banded 128 + integrated tail block (bm=128)
  gemm_bt<1, 129, 1, 16, 1><<<129, 256, 0, stream>>>(xcb, wXB, nullptr, xdbl, 2048);
  delta_kernel<<<dim3(2051, 8), 256, 0, stream>>>(xdbl, W_dt, b_dt, delta);

  scan_pass1<<<4160, 256, 0, stream>>>(xcb, delta, xdbl, sdbuf, qbuf);
  scan_boundary<<<dim3(128, B8), 256, 0, stream>>>(sdbuf, qbuf);
  scan_pass2<<<4160, 256, 0, stream>>>(xcb, delta, xdbl, qbuf, ybuf);

  // gemm<2>: banded 1024 + 8 integrated tail blocks (bm=128, bn=0..7)
  gemm_bt<2, 129, 8, 16, 1><<<1032, 256, 0, stream>>>(ybuf, wOutB, b_out, (float*)d_out, 2048);
}

// Round 11
// 521.184 us; speedup vs baseline: 1.3391x; 1.0317x over previous
//
#include <hip/hip_runtime.h>
#include <cstdint>
#include <cstddef>

#define B8 8
#define LSEQ 2048
#define LC 2051
#define DMODEL 1024
#define DIM 2048
#define LPAD 2054           // 3 + 2048 + 3 zero-padded rows per batch
#define M2 16408            // B8*LC valid rows
#define M2P 16512           // padded to multiple of 128
#define CS 32               // scan chunk size
#define NCH 65              // ceil(2051/32)

typedef __attribute__((ext_vector_type(8))) short short8;
typedef __attribute__((ext_vector_type(4))) float floatx4;
typedef __attribute__((ext_vector_type(2))) float float2v;
typedef __attribute__((address_space(3))) unsigned short lds_ushort;

// A_n = -exp(-n/3), n=0..15
__device__ __constant__ float AeT[16] = {
  -1.0f,          -0.71653131f, -0.51341712f, -0.36787944f,
  -0.26359714f,   -0.18887560f, -0.13533528f, -0.09697208f,
  -0.06948345f,   -0.04978707f, -0.03567399f, -0.02556154f,
  -0.01831564f,   -0.01312373f, -0.00940356f, -0.00673795f};

#define LOG2E 1.44269504088896f

__device__ __forceinline__ float bf2f(unsigned short h) {
  union { unsigned int u; float f; } v; v.u = ((unsigned int)h) << 16; return v.f;
}
__device__ __forceinline__ unsigned short f2bf(float f) {
  union { float f; unsigned int u; } v; v.f = f;
  unsigned int r = (v.u + 0x7FFFu + ((v.u >> 16) & 1u)) >> 16;
  return (unsigned short)r;
}

// ---- packed fp32 helpers (VOP3P). One scalar operand allowed per instr. ----
__device__ __forceinline__ float2v pk_mul_vv(float2v a, float2v b) {
  float2v d; asm("v_pk_mul_f32 %0, %1, %2" : "=v"(d) : "v"(a), "v"(b)); return d;
}
__device__ __forceinline__ float2v pk_mul_sv(float2v bs, float2v a) {   // bs wave-uniform (SGPR)
  float2v d; asm("v_pk_mul_f32 %0, %1, %2" : "=v"(d) : "s"(bs), "v"(a)); return d;
}
__device__ __forceinline__ float2v pk_fma_vvv(float2v a, float2v b, float2v c) {
  float2v d; asm("v_pk_fma_f32 %0, %1, %2, %3" : "=v"(d) : "v"(a), "v"(b), "v"(c)); return d;
}
__device__ __forceinline__ float2v pk_fma_vsv(float2v a, float2v bs, float2v c) { // bs uniform
  float2v d; asm("v_pk_fma_f32 %0, %1, %2, %3" : "=v"(d) : "v"(a), "s"(bs), "v"(c)); return d;
}
__device__ __forceinline__ float2v pk_add_vv(float2v a, float2v b) {
  float2v d; asm("v_pk_add_f32 %0, %1, %2" : "=v"(d) : "v"(a), "v"(b)); return d;
}
__device__ __forceinline__ float exp2_raw(float x) {   // 2^x
  float d; asm("v_exp_f32 %0, %1" : "=v"(d) : "v"(x)); return d;
}

// ---- opaque LDS read (r7 tool): compiler cannot alias-track this against
// global_load_lds, so it cannot insert a conservative vmcnt(0) before it.
__device__ __forceinline__ short8 ds_read_b128_(const lds_ushort* p) {
  floatx4 d;
  unsigned addr = (unsigned)(size_t)p;
  asm volatile("ds_read_b128 %0, %1" : "=v"(d) : "v"(addr));
  return __builtin_bit_cast(short8, d);
}

// ---------------- fused init: x->bf16, W_in/W_out/W_x->bf16, zero pads ----------------
// range-dispatched single launch (saves 4 launch overheads)
__global__ __launch_bounds__(256) void init_kernel(const float* __restrict__ x,
                                                   const float* __restrict__ W_in,
                                                   const float* __restrict__ W_out,
                                                   const float* __restrict__ W_x,
                                                   unsigned short* __restrict__ xA,
                                                   unsigned short* __restrict__ wInB,
                                                   unsigned short* __restrict__ wOutB,
                                                   unsigned short* __restrict__ wXB,
                                                   unsigned short* __restrict__ xp) {
  const int gid = blockIdx.x;
  const float* in; unsigned short* out; int i;
  if (gid < 8192)        { in = x;     out = xA;    i = gid * 256 + threadIdx.x; }
  else if (gid < 9216)   { in = W_in;  out = wInB;  i = (gid - 8192) * 256 + threadIdx.x; }
  else if (gid < 10240)  { in = W_out; out = wOutB; i = (gid - 9216) * 256 + threadIdx.x; }
  else if (gid < 10288)  { in = W_x;   out = wXB;   i = (gid - 10240) * 256 + threadIdx.x; }
  else {
    // zero pads: 48 blocks
    int ii = (gid - 10288) * 256 + threadIdx.x;   // 0..12287
    int b = ii / 1536;
    int r6 = (ii % 1536) / 256;
    int dd = (ii % 256) * 8;
    int row = (r6 < 3) ? r6 : (2048 + r6);
    *(uint4*)(xp + ((size_t)b * LPAD + row) * DIM + dd) = make_uint4(0, 0, 0, 0);
    return;
  }
  const float4* p = (const float4*)in + (size_t)i * 2;
  float4 a = p[0], b = p[1];
  uint4 o;
  o.x = (unsigned)f2bf(a.x) | ((unsigned)f2bf(a.y) << 16);
  o.y = (unsigned)f2bf(a.z) | ((unsigned)f2bf(a.w) << 16);
  o.z = (unsigned)f2bf(b.x) | ((unsigned)f2bf(b.y) << 16);
  o.w = (unsigned)f2bf(b.z) | ((unsigned)f2bf(b.w) << 16);
  *((uint4*)out + i) = o;
}

// ---------------- depthwise conv1d, 16 t per block (sliding window) ----------------
__global__ __launch_bounds__(256) void conv_kernel(const unsigned short* __restrict__ xp,
                                                   const float* __restrict__ conv_w,
                                                   const float* __restrict__ conv_b,
                                                   unsigned short* __restrict__ xc) {
  const int tc0 = blockIdx.x * 16;
  const int b = blockIdx.y;
  const int d0 = threadIdx.x * 8;

  float4 cw[8];
#pragma unroll
  for (int j = 0; j < 8; ++j) cw[j] = *(const float4*)(conv_w + (size_t)(d0 + j) * 4);
  float cb[8];
  {
    const float4* cb4 = (const float4*)(conv_b + d0);
    float4 c0 = cb4[0], c1 = cb4[1];
    cb[0] = c0.x; cb[1] = c0.y; cb[2] = c0.z; cb[3] = c0.w;
    cb[4] = c1.x; cb[5] = c1.y; cb[6] = c1.z; cb[7] = c1.w;
  }

  const unsigned short* base = xp + ((size_t)b * LPAD + tc0) * DIM + d0;
  unsigned short* outp = xc + ((size_t)b * LC + tc0) * DIM + d0;

  auto loadrow = [&](float (&w)[8], int r) {
    uint4 v = *(const uint4*)(base + (size_t)r * DIM);
    w[0] = bf2f(v.x & 0xffff); w[1] = bf2f(v.x >> 16);
    w[2] = bf2f(v.y & 0xffff); w[3] = bf2f(v.y >> 16);
    w[4] = bf2f(v.z & 0xffff); w[5] = bf2f(v.z >> 16);
    w[6] = bf2f(v.w & 0xffff); w[7] = bf2f(v.w >> 16);
  };

  float wa[8], wb[8], wc[8];
  loadrow(wa, 0); loadrow(wb, 1); loadrow(wc, 2);
#pragma unroll
  for (int i = 0; i < 16; ++i) {
    float wd[8];
    loadrow(wd, i + 3);
    if (tc0 + i < LC) {
      float acc[8];
#pragma unroll
      for (int j = 0; j < 8; ++j) {
        acc[j] = cb[j];
        acc[j] = fmaf(wa[j], cw[j].x, acc[j]);
        acc[j] = fmaf(wb[j], cw[j].y, acc[j]);
        acc[j] = fmaf(wc[j], cw[j].z, acc[j]);
        acc[j] = fmaf(wd[j], cw[j].w, acc[j]);
      }
      uint4 o;
      o.x = (unsigned)f2bf(acc[0]) | ((unsigned)f2bf(acc[1]) << 16);
      o.y = (unsigned)f2bf(acc[2]) | ((unsigned)f2bf(acc[3]) << 16);
      o.z = (unsigned)f2bf(acc[4]) | ((unsigned)f2bf(acc[5]) << 16);
      o.w = (unsigned)f2bf(acc[6]) | ((unsigned)f2bf(acc[7]) << 16);
      *(uint4*)(outp + (size_t)i * DIM) = o;
    }
#pragma unroll
    for (int j = 0; j < 8; ++j) { wa[j] = wb[j]; wb[j] = wc[j]; wc[j] = wd[j]; }
  }
}

#define GAS(p) ((const __attribute__((address_space(1))) void*)(p))
#define LAS(p) ((__attribute__((address_space(3))) void*)(p))

// ---------------- bf16 MFMA GEMM: BK=64, one-barrier double-buffer ----------------
// Per iter: STAGE(t+1 -> buf^1) FIRST (stays in flight under this iter's compute),
// then opaque-asm ds_read of buf (no compiler vmcnt(0) insertion), lgkmcnt(0)+
// sched_barrier, 32 MFMA, then ONE __syncthreads() (its vmcnt0 drain = t+1 ready;
// all reads of buf completed before it via lgkmcnt(0)). LDS 64KB -> 2 blocks/CU.
// Swizzle (both sides, rule #21): phys_blk = log_blk ^ (row&7); 0 conflicts (r9).
// Mapping: XCD-banded main + optional integrated tail (TAIL=1).
template <int MODE, int NBM, int NBN, int LX, int TAIL>
__global__ __launch_bounds__(256) void gemm_bt(const unsigned short* __restrict__ A,
                                               const unsigned short* __restrict__ Bw,
                                               const float* __restrict__ bias,
                                               void* __restrict__ Cout, int K) {
  const int gid = blockIdx.x;
  const int mainBlocks = 8 * LX * NBN;
  int bm, bn;
  if (TAIL && gid >= mainBlocks) {
    const int e = gid - mainBlocks;
    bm = 8 * LX + e / NBN;
    bn = e % NBN;
  } else {
    const int xcd = gid & 7;
    const int j = gid >> 3;
    bm = xcd * LX + (j % LX);
    bn = j / LX;
  }
  if (bm >= NBM) return;

  __shared__ __align__(16) unsigned short As[2][128 * 64];   // 2 x 16KB
  __shared__ __align__(16) unsigned short Bs[2][128 * 64];   // 2 x 16KB
  const int tid = threadIdx.x;
  const int lane = tid & 63, wave = tid >> 6;
  const int wr = wave >> 1, wc = wave & 1;

  floatx4 acc[4][4];
#pragma unroll
  for (int i = 0; i < 4; ++i)
#pragma unroll
    for (int j2 = 0; j2 < 4; ++j2) acc[i][j2] = (floatx4){0.f, 0.f, 0.f, 0.f};

  // staging: load L covers line = L*256+tid; row = L*32 + (tid>>3), phys_blk = tid&7,
  // logical blk = phys ^ (row&7) = (tid&7)^((tid>>3)&7)  (inverse swizzle on global src).
  const int srow = tid >> 3;
  const int scol = ((tid & 7) ^ ((tid >> 3) & 7)) * 8;
  const unsigned short* Ab[4];
  const unsigned short* Bb[4];
#pragma unroll
  for (int L = 0; L < 4; ++L) {
    Ab[L] = A  + (size_t)(bm * 128 + L * 32 + srow) * K + scol;
    Bb[L] = Bw + (size_t)(bn * 128 + L * 32 + srow) * K + scol;
  }

  const int fr = lane & 15;
  const int hi = lane >> 4;
  const int fx = fr & 7;

  auto STAGE = [&](int buf, int k0) {
#pragma unroll
    for (int L = 0; L < 4; ++L) {
      __builtin_amdgcn_global_load_lds(GAS(Ab[L] + k0), LAS(&As[buf][L * 2048 + tid * 8]), 16, 0, 0);
      __builtin_amdgcn_global_load_lds(GAS(Bb[L] + k0), LAS(&Bs[buf][L * 2048 + tid * 8]), 16, 0, 0);
    }
  };

  const int NT = K >> 6;
  STAGE(0, 0);
  asm volatile("s_waitcnt vmcnt(0)");
  __syncthreads();

  int cur = 0;
  for (int t = 0; t < NT; ++t) {
    if (t + 1 < NT) STAGE(cur ^ 1, (t + 1) * 64);

    const lds_ushort* tA = (const lds_ushort*)LAS(&As[cur][0]);
    const lds_ushort* tB = (const lds_ushort*)LAS(&Bs[cur][0]);
#pragma unroll
    for (int kk = 0; kk < 2; ++kk) {
      const int pb = ((kk * 4 + hi) ^ fx) * 8;
      short8 af[4], bf[4];
#pragma unroll
      for (int mt = 0; mt < 4; ++mt) af[mt] = ds_read_b128_(tA + (wr * 64 + mt * 16 + fr) * 64 + pb);
#pragma unroll
      for (int nt = 0; nt < 4; ++nt) bf[nt] = ds_read_b128_(tB + (wc * 64 + nt * 16 + fr) * 64 + pb);
      asm volatile("s_waitcnt lgkmcnt(0)");
      __builtin_amdgcn_sched_barrier(0);
      __builtin_amdgcn_s_setprio(1);
#pragma unroll
      for (int mt = 0; mt < 4; ++mt)
#pragma unroll
        for (int nt = 0; nt < 4; ++nt)
          acc[mt][nt] = __builtin_amdgcn_mfma_f32_16x16x32_bf16(af[mt], bf[nt], acc[mt][nt], 0, 0, 0);
      __builtin_amdgcn_s_setprio(0);
    }
    __syncthreads();   // drains vmcnt(0): t+1 staged; all waves' reads of cur done
    cur ^= 1;
  }

  const int er = (lane >> 4) * 4, ec = lane & 15;
#pragma unroll
  for (int mt = 0; mt < 4; ++mt) {
#pragma unroll
    for (int nt = 0; nt < 4; ++nt) {
#pragma unroll
      for (int i = 0; i < 4; ++i) {
        int r = bm * 128 + wr * 64 + mt * 16 + er + i;
        int c = bn * 128 + wc * 64 + nt * 16 + ec;
        float v = acc[mt][nt][i];
        if constexpr (MODE == 0) {
          int bb = r >> 11, t = r & 2047;
          ((unsigned short*)Cout)[((size_t)bb * LPAD + 3 + t) * DIM + c] = f2bf(v + bias[c]);
        } else if constexpr (MODE == 1) {
          if (r < M2 && c < 48) ((float*)Cout)[(size_t)r * 48 + c] = v;
        } else {
          if (r < M2) ((float*)Cout)[(size_t)r * DMODEL + c] = v + bias[c];
        }
      }
    }
  }
}

// ---------------- delta precompute: softplus(d_raw @ W_dt.T + b_dt) -> bf16 ----------------
__global__ __launch_bounds__(256) void delta_kernel(const float* __restrict__ xdbl,
                                                    const float* __restrict__ W_dt,
                                                    const float* __restrict__ b_dt,
                                                    unsigned short* __restrict__ delta) {
  const int d = blockIdx.y * 256 + threadIdx.x;
  const int r0 = blockIdx.x * 8;
  float wv[16];
  const float4* wp = (const float4*)(W_dt + (size_t)d * 16);
#pragma unroll
  for (int q = 0; q < 4; ++q) {
    float4 t = wp[q];
    wv[q * 4 + 0] = t.x; wv[q * 4 + 1] = t.y; wv[q * 4 + 2] = t.z; wv[q * 4 + 3] = t.w;
  }
  const float bd = b_dt[d];
#pragma unroll
  for (int j = 0; j < 8; ++j) {
    const float* dr = xdbl + (size_t)(r0 + j) * 48;   // uniform -> s_load
    float z0 = bd, z1 = 0.f, z2 = 0.f, z3 = 0.f;
#pragma unroll
    for (int n = 0; n < 16; n += 4) {
      z0 = fmaf(dr[n + 0], wv[n + 0], z0);
      z1 = fmaf(dr[n + 1], wv[n + 1], z1);
      z2 = fmaf(dr[n + 2], wv[n + 2], z2);
      z3 = fmaf(dr[n + 3], wv[n + 3], z3);
    }
    float z = (z0 + z1) + (z2 + z3);
    float dl = (z > 20.f) ? z : __logf(1.f + __expf(z));
    delta[(size_t)(r0 + j) * DIM + d] = f2bf(dl);
  }
}

// ---------------- chunked scan, pass 1: per-chunk (sumd, q) -> bf16 ----------------
__global__ __launch_bounds__(256) void scan_pass1(const unsigned short* __restrict__ xc,
                                                  const unsigned short* __restrict__ dl,
                                                  const float* __restrict__ xd,
                                                  unsigned short* __restrict__ sdbuf,
                                                  unsigned short* __restrict__ qbuf) {
  const int wid = __builtin_amdgcn_readfirstlane((int)(threadIdx.x >> 6));
  const int lane = threadIdx.x & 63;
  const int W = blockIdx.x * 4 + wid;
  const int dg = W & 31;
  const int rest = W >> 5;
  const int c = rest % NCH;
  const int b = rest / NCH;
  const int d = dg * 64 + lane;
  const int t0 = c * CS;
  const int nst = (t0 + CS <= LC) ? CS : (LC - t0);

  float2v A2L[8];
#pragma unroll
  for (int i = 0; i < 8; ++i)
    A2L[i] = (float2v){AeT[2 * i] * LOG2E, AeT[2 * i + 1] * LOG2E};

  float2v h2[8];
#pragma unroll
  for (int i = 0; i < 8; ++i) h2[i] = (float2v){0.f, 0.f};
  float sumd = 0.f;

  const size_t row0 = (size_t)b * LC + t0;
  const float* xdb = xd + row0 * 48 + 16;            // B cols (uniform -> s_load)
  const unsigned short* xcp = xc + row0 * DIM + d;
  const unsigned short* dp  = dl + row0 * DIM + d;

  auto body = [&](int s) {
    float2v Bv[8];
#pragma unroll
    for (int j = 0; j < 8; ++j) Bv[j] = *(const float2v*)(xdb + (size_t)s * 48 + 2 * j);
    float dlt = bf2f(dp[(size_t)s * DIM]);
    float xcv = bf2f(xcp[(size_t)s * DIM]);
    sumd += dlt;
    float2v dlt2 = (float2v){dlt, dlt};
    float2v xcv2 = (float2v){xcv, xcv};
#pragma unroll
    for (int i = 0; i < 8; ++i) {
      float2v arg = pk_mul_vv(dlt2, A2L[i]);
      float e0 = exp2_raw(arg.x), e1 = exp2_raw(arg.y);
      float2v e2 = (float2v){e0, e1};
      h2[i] = pk_fma_vvv(h2[i], e2, pk_mul_sv(Bv[i], xcv2));
    }
  };

  if (nst == CS) {
#pragma unroll
    for (int s = 0; s < CS; ++s) body(s);
  } else {
    for (int s = 0; s < nst; ++s) body(s);
  }

  sdbuf[((size_t)(b * NCH + c) << 11) + d] = f2bf(sumd);
  const size_t base = ((size_t)(b * NCH + c) * 16) * 2048 + d;
#pragma unroll
  for (int i = 0; i < 8; ++i) {
    qbuf[base + ((size_t)(2 * i) << 11)]     = f2bf(h2[i].x);
    qbuf[base + ((size_t)(2 * i + 1) << 11)] = f2bf(h2[i].y);
  }
}

// ---------------- boundary scan: 1 lane per (b,d,n); h across chunks, h_init over q ----
__global__ __launch_bounds__(256) void scan_boundary(const unsigned short* __restrict__ sdbuf,
                                                     unsigned short* __restrict__ qbuf) {
  const int tid = threadIdx.x;
  const int n = tid >> 4;                          // 0..15
  const int d = blockIdx.x * 16 + (tid & 15);      // 0..2047
  const int b = blockIdx.y;
  const float aL = AeT[n] * LOG2E;
  float h = 0.f;
  for (int c = 0; c < NCH; ++c) {
    const size_t sbase = ((size_t)(b * NCH + c) << 11);
    const float sd = bf2f(sdbuf[sbase + d]);
    const size_t base = (sbase << 4) + ((size_t)n << 11) + d;
    const float qv = bf2f(qbuf[base]);
    const float Pv = exp2_raw(sd * aL);
    qbuf[base] = f2bf(h);                          // h at chunk start
    h = fmaf(Pv, h, qv);
  }
}

// ---------------- chunked scan, pass 2: recompute with h_init, emit y ----------------
// NOTE: y aliases dl (in-place, same [r][d] layout); only the owning thread touches
// each element and reads precede the store for that row.
__global__ __launch_bounds__(256) void scan_pass2(const unsigned short* __restrict__ xc,
                                                  const unsigned short* __restrict__ dl,
                                                  const float* __restrict__ xd,
                                                  const unsigned short* __restrict__ hinit,
                                                  unsigned short* __restrict__ y) {
  const int wid = __builtin_amdgcn_readfirstlane((int)(threadIdx.x >> 6));
  const int lane = threadIdx.x & 63;
  const int W = blockIdx.x * 4 + wid;
  const int dg = W & 31;
  const int rest = W >> 5;
  const int c = rest % NCH;
  const int b = rest / NCH;
  const int d = dg * 64 + lane;
  const int t0 = c * CS;
  const int nst = (t0 + CS <= LC) ? CS : (LC - t0);

  float2v A2L[8];
#pragma unroll
  for (int i = 0; i < 8; ++i)
    A2L[i] = (float2v){AeT[2 * i] * LOG2E, AeT[2 * i + 1] * LOG2E};

  const size_t base = ((size_t)(b * NCH + c) * 16) * 2048 + d;
  float2v h2[8];
#pragma unroll
  for (int i = 0; i < 8; ++i)
    h2[i] = (float2v){bf2f(hinit[base + ((size_t)(2 * i) << 11)]),
                      bf2f(hinit[base + ((size_t)(2 * i + 1) << 11)])};

  const size_t row0 = (size_t)b * LC + t0;
  const float* xdb = xd + row0 * 48 + 16;            // B at [j], C at [16+j]
  const unsigned short* xcp = xc + row0 * DIM + d;
  const unsigned short* dp  = dl + row0 * DIM + d;
  unsigned short* yp = y + row0 * DIM + d;

  auto body = [&](int s) {
    float2v Bv[8], Cv[8];
#pragma unroll
    for (int j = 0; j < 8; ++j) {
      Bv[j] = *(const float2v*)(xdb + (size_t)s * 48 + 2 * j);
      Cv[j] = *(const float2v*)(xdb + (size_t)s * 48 + 16 + 2 * j);
    }
    float dlt = bf2f(dp[(size_t)s * DIM]);
    float xcv = bf2f(xcp[(size_t)s * DIM]);
    float2v dlt2 = (float2v){dlt, dlt};
    float2v xcv2 = (float2v){xcv, xcv};
    float2v y2[4];
#pragma unroll
    for (int i = 0; i < 4; ++i) y2[i] = (float2v){0.f, 0.f};
#pragma unroll
    for (int i = 0; i < 8; ++i) {
      float2v arg = pk_mul_vv(dlt2, A2L[i]);
      float e0 = exp2_raw(arg.x), e1 = exp2_raw(arg.y);
      float2v e2 = (float2v){e0, e1};
      h2[i] = pk_fma_vvv(h2[i], e2, pk_mul_sv(Bv[i], xcv2));
      y2[i & 3] = pk_fma_vsv(h2[i], Cv[i], y2[i & 3]);
    }
    float2v s01 = pk_add_vv(y2[0], y2[1]);
    float2v s23 = pk_add_vv(y2[2], y2[3]);
    float2v st = pk_add_vv(s01, s23);
    yp[(size_t)s * DIM] = f2bf(st.x + st.y);
  };

  if (nst == CS) {
#pragma unroll
    for (int s = 0; s < CS; ++s) body(s);
  } else {
    for (int s = 0; s < nst; ++s) body(s);
  }
}

// ---------------- launch ----------------
extern "C" void kernel_launch(void* const* d_in, const int* in_sizes, int n_in,
                              void* d_out, int out_size, void* d_ws, size_t ws_size,
                              hipStream_t stream) {
  const float* x      = (const float*)d_in[0];
  const float* W_in   = (const float*)d_in[1];
  const float* b_in   = (const float*)d_in[2];
  const float* conv_w = (const float*)d_in[3];
  const float* conv_b = (const float*)d_in[4];
  const float* W_x    = (const float*)d_in[5];
  const float* W_dt   = (const float*)d_in[6];
  const float* b_dt   = (const float*)d_in[7];
  const float* W_out  = (const float*)d_in[8];
  const float* b_out  = (const float*)d_in[9];

  char* w = (char*)d_ws;
  // region 0 (67.63 MB): xp (LPAD layout) -> delta [M2P][DIM] -> y (in-place over delta)
  unsigned short* xp    = (unsigned short*)w;
  unsigned short* delta = (unsigned short*)w;
  unsigned short* ybuf  = (unsigned short*)w;
  size_t off = (size_t)M2P * DIM * 2;                                  // 67,633,152
  unsigned short* xcb  = (unsigned short*)(w + off); off += (size_t)M2P * DIM * 2;
  size_t xA_off = off;                                                 // 135,266,304
  unsigned short* xA   = (unsigned short*)(w + off); off += (size_t)16384 * 1024 * 2;
  unsigned short* wInB = (unsigned short*)(w + off); off += (size_t)2048 * 1024 * 2;
  unsigned short* wOutB= (unsigned short*)(w + off); off += (size_t)1024 * 2048 * 2;
  unsigned short* wXB  = (unsigned short*)(w + off); off += (size_t)128 * 2048 * 2;
  float* xdbl          = (float*)(w + off);          off += (size_t)M2 * 48 * 4;
  // sdbuf (2.13 MB bf16) + qbuf (34.08 MB bf16) reuse xA+wInB region (dead after gemm1)
  unsigned short* sdbuf = (unsigned short*)(w + xA_off);
  unsigned short* qbuf  = (unsigned short*)(w + xA_off + (size_t)B8 * NCH * 2048 * 2);
  (void)ws_size; (void)in_sizes; (void)n_in; (void)out_size;

  init_kernel<<<10336, 256, 0, stream>>>(x, W_in, W_out, W_x, xA, wInB, wOutB, wXB, xp);

  // gemm<0>: 128 bm tiles exact
  gemm_bt<0, 128, 16, 16, 0><<<2048, 256, 0, stream>>>(xA, wInB, b_in, xp, 1024);
  conv_kernel<<<dim3(129, B8), 256, 0, stream>>>(xp, conv_w, conv_b, xcb);
  // gemm<1>: banded 128 + integrated tail block (bm=128)
  gemm_bt<1, 129, 1, 16, 1><<<129, 256, 0, stream>>>(xcb, wXB, nullptr, xdbl, 2048);
  delta_kernel<<<dim3(2051, 8), 256, 0, stream>>>(xdbl, W_dt, b_dt, delta);

  scan_pass1<<<4160, 256, 0, stream>>>(xcb, delta, xdbl, sdbuf, qbuf);
  scan_boundary<<<dim3(128, B8), 256, 0, stream>>>(sdbuf, qbuf);
  scan_pass2<<<4160, 256, 0, stream>>>(xcb, delta, xdbl, qbuf, ybuf);

  // gemm<2>: banded 1024 + 8 integrated tail blocks (bm=128, bn=0..7)
  gemm_bt<2, 129, 8, 16, 1><<<1032, 256, 0, stream>>>(ybuf, wOutB, b_out, (float*)d_out, 2048);
}

// Round 12
// 511.292 us; speedup vs baseline: 1.3650x; 1.0193x over previous
//
#include <hip/hip_runtime.h>
#include <cstdint>
#include <cstddef>

#define B8 8
#define LSEQ 2048
#define LC 2051
#define DMODEL 1024
#define DIM 2048
#define LPAD 2054           // 3 + 2048 + 3 zero-padded rows per batch
#define M2 16408            // B8*LC valid rows
#define M2P 16512           // padded to multiple of 128
#define CS 32               // scan chunk size
#define NCH 65              // ceil(2051/32)

typedef __attribute__((ext_vector_type(8))) short short8;
typedef __attribute__((ext_vector_type(4))) float floatx4;
typedef __attribute__((ext_vector_type(2))) float float2v;
typedef __attribute__((address_space(3))) unsigned short lds_ushort;

// A_n = -exp(-n/3), n=0..15
__device__ __constant__ float AeT[16] = {
  -1.0f,          -0.71653131f, -0.51341712f, -0.36787944f,
  -0.26359714f,   -0.18887560f, -0.13533528f, -0.09697208f,
  -0.06948345f,   -0.04978707f, -0.03567399f, -0.02556154f,
  -0.01831564f,   -0.01312373f, -0.00940356f, -0.00673795f};

#define LOG2E 1.44269504088896f

__device__ __forceinline__ float bf2f(unsigned short h) {
  union { unsigned int u; float f; } v; v.u = ((unsigned int)h) << 16; return v.f;
}
__device__ __forceinline__ unsigned short f2bf(float f) {
  union { float f; unsigned int u; } v; v.f = f;
  unsigned int r = (v.u + 0x7FFFu + ((v.u >> 16) & 1u)) >> 16;
  return (unsigned short)r;
}

// ---- packed fp32 helpers (VOP3P). One scalar operand allowed per instr. ----
__device__ __forceinline__ float2v pk_mul_vv(float2v a, float2v b) {
  float2v d; asm("v_pk_mul_f32 %0, %1, %2" : "=v"(d) : "v"(a), "v"(b)); return d;
}
__device__ __forceinline__ float2v pk_mul_sv(float2v bs, float2v a) {   // bs wave-uniform (SGPR)
  float2v d; asm("v_pk_mul_f32 %0, %1, %2" : "=v"(d) : "s"(bs), "v"(a)); return d;
}
__device__ __forceinline__ float2v pk_fma_vvv(float2v a, float2v b, float2v c) {
  float2v d; asm("v_pk_fma_f32 %0, %1, %2, %3" : "=v"(d) : "v"(a), "v"(b), "v"(c)); return d;
}
__device__ __forceinline__ float2v pk_fma_vsv(float2v a, float2v bs, float2v c) { // bs uniform
  float2v d; asm("v_pk_fma_f32 %0, %1, %2, %3" : "=v"(d) : "v"(a), "s"(bs), "v"(c)); return d;
}
__device__ __forceinline__ float2v pk_add_vv(float2v a, float2v b) {
  float2v d; asm("v_pk_add_f32 %0, %1, %2" : "=v"(d) : "v"(a), "v"(b)); return d;
}
__device__ __forceinline__ float exp2_raw(float x) {   // 2^x
  float d; asm("v_exp_f32 %0, %1" : "=v"(d) : "v"(x)); return d;
}

// ---- opaque LDS read (r7 tool): compiler cannot alias-track this against
// global_load_lds, so it cannot insert a conservative vmcnt(0) before it.
__device__ __forceinline__ short8 ds_read_b128_(const lds_ushort* p) {
  floatx4 d;
  unsigned addr = (unsigned)(size_t)p;
  asm volatile("ds_read_b128 %0, %1" : "=v"(d) : "v"(addr));
  return __builtin_bit_cast(short8, d);
}

// ---------------- fused init: x->bf16, W_in/W_out/W_x->bf16, zero pads ----------------
__global__ __launch_bounds__(256) void init_kernel(const float* __restrict__ x,
                                                   const float* __restrict__ W_in,
                                                   const float* __restrict__ W_out,
                                                   const float* __restrict__ W_x,
                                                   unsigned short* __restrict__ xA,
                                                   unsigned short* __restrict__ wInB,
                                                   unsigned short* __restrict__ wOutB,
                                                   unsigned short* __restrict__ wXB,
                                                   unsigned short* __restrict__ xp) {
  const int gid = blockIdx.x;
  const float* in; unsigned short* out; int i;
  if (gid < 8192)        { in = x;     out = xA;    i = gid * 256 + threadIdx.x; }
  else if (gid < 9216)   { in = W_in;  out = wInB;  i = (gid - 8192) * 256 + threadIdx.x; }
  else if (gid < 10240)  { in = W_out; out = wOutB; i = (gid - 9216) * 256 + threadIdx.x; }
  else if (gid < 10288)  { in = W_x;   out = wXB;   i = (gid - 10240) * 256 + threadIdx.x; }
  else {
    int ii = (gid - 10288) * 256 + threadIdx.x;   // 0..12287
    int b = ii / 1536;
    int r6 = (ii % 1536) / 256;
    int dd = (ii % 256) * 8;
    int row = (r6 < 3) ? r6 : (2048 + r6);
    *(uint4*)(xp + ((size_t)b * LPAD + row) * DIM + dd) = make_uint4(0, 0, 0, 0);
    return;
  }
  const float4* p = (const float4*)in + (size_t)i * 2;
  float4 a = p[0], b = p[1];
  uint4 o;
  o.x = (unsigned)f2bf(a.x) | ((unsigned)f2bf(a.y) << 16);
  o.y = (unsigned)f2bf(a.z) | ((unsigned)f2bf(a.w) << 16);
  o.z = (unsigned)f2bf(b.x) | ((unsigned)f2bf(b.y) << 16);
  o.w = (unsigned)f2bf(b.z) | ((unsigned)f2bf(b.w) << 16);
  *((uint4*)out + i) = o;
}

// ---------------- depthwise conv1d, 16 t per block (sliding window) ----------------
__global__ __launch_bounds__(256) void conv_kernel(const unsigned short* __restrict__ xp,
                                                   const float* __restrict__ conv_w,
                                                   const float* __restrict__ conv_b,
                                                   unsigned short* __restrict__ xc) {
  const int tc0 = blockIdx.x * 16;
  const int b = blockIdx.y;
  const int d0 = threadIdx.x * 8;

  float4 cw[8];
#pragma unroll
  for (int j = 0; j < 8; ++j) cw[j] = *(const float4*)(conv_w + (size_t)(d0 + j) * 4);
  float cb[8];
  {
    const float4* cb4 = (const float4*)(conv_b + d0);
    float4 c0 = cb4[0], c1 = cb4[1];
    cb[0] = c0.x; cb[1] = c0.y; cb[2] = c0.z; cb[3] = c0.w;
    cb[4] = c1.x; cb[5] = c1.y; cb[6] = c1.z; cb[7] = c1.w;
  }

  const unsigned short* base = xp + ((size_t)b * LPAD + tc0) * DIM + d0;
  unsigned short* outp = xc + ((size_t)b * LC + tc0) * DIM + d0;

  auto loadrow = [&](float (&w)[8], int r) {
    uint4 v = *(const uint4*)(base + (size_t)r * DIM);
    w[0] = bf2f(v.x & 0xffff); w[1] = bf2f(v.x >> 16);
    w[2] = bf2f(v.y & 0xffff); w[3] = bf2f(v.y >> 16);
    w[4] = bf2f(v.z & 0xffff); w[5] = bf2f(v.z >> 16);
    w[6] = bf2f(v.w & 0xffff); w[7] = bf2f(v.w >> 16);
  };

  float wa[8], wb[8], wc[8];
  loadrow(wa, 0); loadrow(wb, 1); loadrow(wc, 2);
#pragma unroll
  for (int i = 0; i < 16; ++i) {
    float wd[8];
    loadrow(wd, i + 3);
    if (tc0 + i < LC) {
      float acc[8];
#pragma unroll
      for (int j = 0; j < 8; ++j) {
        acc[j] = cb[j];
        acc[j] = fmaf(wa[j], cw[j].x, acc[j]);
        acc[j] = fmaf(wb[j], cw[j].y, acc[j]);
        acc[j] = fmaf(wc[j], cw[j].z, acc[j]);
        acc[j] = fmaf(wd[j], cw[j].w, acc[j]);
      }
      uint4 o;
      o.x = (unsigned)f2bf(acc[0]) | ((unsigned)f2bf(acc[1]) << 16);
      o.y = (unsigned)f2bf(acc[2]) | ((unsigned)f2bf(acc[3]) << 16);
      o.z = (unsigned)f2bf(acc[4]) | ((unsigned)f2bf(acc[5]) << 16);
      o.w = (unsigned)f2bf(acc[6]) | ((unsigned)f2bf(acc[7]) << 16);
      *(uint4*)(outp + (size_t)i * DIM) = o;
    }
#pragma unroll
    for (int j = 0; j < 8; ++j) { wa[j] = wb[j]; wb[j] = wc[j]; wc[j] = wd[j]; }
  }
}

#define GAS(p) ((const __attribute__((address_space(1))) void*)(p))
#define LAS(p) ((__attribute__((address_space(3))) void*)(p))

// ---------------- bf16 MFMA GEMM: BK=64, one-barrier double-buffer ----------------
// Per iter: STAGE(t+1 -> buf^1) first, opaque-asm ds_read of buf, lgkmcnt(0)+sched_barrier,
// 32 MFMA, ONE __syncthreads(). Swizzle both sides: phys_blk = log_blk ^ (row&7); 0 conflicts.
// Mapping: XCD-banded main + optional integrated tail (TAIL=1).
// SPLITK=1 (MODE 1): gid = bm*8+ks; ks = gid&7 (== XCD -> each XCD keeps one 64KB B-slice
// L2-resident, A fetched once); each block does K/8 only; partials -> part[ks][r][48].
template <int MODE, int NBM, int NBN, int LX, int TAIL, int SPLITK>
__global__ __launch_bounds__(256) void gemm_bt(const unsigned short* __restrict__ A,
                                               const unsigned short* __restrict__ Bw,
                                               const float* __restrict__ bias,
                                               void* __restrict__ Cout, int K) {
  const int gid = blockIdx.x;
  const int mainBlocks = 8 * LX * NBN;
  int bm, bn, ks = 0;
  if constexpr (SPLITK) {
    ks = gid & 7;
    bm = gid >> 3;
    bn = 0;
  } else if (TAIL && gid >= mainBlocks) {
    const int e = gid - mainBlocks;
    bm = 8 * LX + e / NBN;
    bn = e % NBN;
  } else {
    const int xcd = gid & 7;
    const int j = gid >> 3;
    bm = xcd * LX + (j % LX);
    bn = j / LX;
  }
  if (bm >= NBM) return;

  __shared__ __align__(16) unsigned short As[2][128 * 64];   // 2 x 16KB
  __shared__ __align__(16) unsigned short Bs[2][128 * 64];   // 2 x 16KB
  const int tid = threadIdx.x;
  const int lane = tid & 63, wave = tid >> 6;
  const int wr = wave >> 1, wc = wave & 1;

  floatx4 acc[4][4];
#pragma unroll
  for (int i = 0; i < 4; ++i)
#pragma unroll
    for (int j2 = 0; j2 < 4; ++j2) acc[i][j2] = (floatx4){0.f, 0.f, 0.f, 0.f};

  // staging: load L covers line = L*256+tid; row = L*32 + (tid>>3), phys_blk = tid&7,
  // logical blk = phys ^ (row&7) = (tid&7)^((tid>>3)&7)  (inverse swizzle on global src).
  const int srow = tid >> 3;
  const int scol = ((tid & 7) ^ ((tid >> 3) & 7)) * 8;
  const unsigned short* Ab[4];
  const unsigned short* Bb[4];
#pragma unroll
  for (int L = 0; L < 4; ++L) {
    Ab[L] = A  + (size_t)(bm * 128 + L * 32 + srow) * K + scol;
    Bb[L] = Bw + (size_t)(bn * 128 + L * 32 + srow) * K + scol;
  }

  const int fr = lane & 15;
  const int hi = lane >> 4;
  const int fx = fr & 7;

  auto STAGE = [&](int buf, int k0) {
#pragma unroll
    for (int L = 0; L < 4; ++L) {
      __builtin_amdgcn_global_load_lds(GAS(Ab[L] + k0), LAS(&As[buf][L * 2048 + tid * 8]), 16, 0, 0);
      __builtin_amdgcn_global_load_lds(GAS(Bb[L] + k0), LAS(&Bs[buf][L * 2048 + tid * 8]), 16, 0, 0);
    }
  };

  const int kbase = SPLITK ? ks * (K >> 3) : 0;
  const int NT = (SPLITK ? (K >> 3) : K) >> 6;
  STAGE(0, kbase);
  asm volatile("s_waitcnt vmcnt(0)");
  __syncthreads();

  int cur = 0;
  for (int t = 0; t < NT; ++t) {
    if (t + 1 < NT) STAGE(cur ^ 1, kbase + (t + 1) * 64);

    const lds_ushort* tA = (const lds_ushort*)LAS(&As[cur][0]);
    const lds_ushort* tB = (const lds_ushort*)LAS(&Bs[cur][0]);
#pragma unroll
    for (int kk = 0; kk < 2; ++kk) {
      const int pb = ((kk * 4 + hi) ^ fx) * 8;
      short8 af[4], bf[4];
#pragma unroll
      for (int mt = 0; mt < 4; ++mt) af[mt] = ds_read_b128_(tA + (wr * 64 + mt * 16 + fr) * 64 + pb);
#pragma unroll
      for (int nt = 0; nt < 4; ++nt) bf[nt] = ds_read_b128_(tB + (wc * 64 + nt * 16 + fr) * 64 + pb);
      asm volatile("s_waitcnt lgkmcnt(0)");
      __builtin_amdgcn_sched_barrier(0);
      __builtin_amdgcn_s_setprio(1);
#pragma unroll
      for (int mt = 0; mt < 4; ++mt)
#pragma unroll
        for (int nt = 0; nt < 4; ++nt)
          acc[mt][nt] = __builtin_amdgcn_mfma_f32_16x16x32_bf16(af[mt], bf[nt], acc[mt][nt], 0, 0, 0);
      __builtin_amdgcn_s_setprio(0);
    }
    __syncthreads();   // drains vmcnt(0): t+1 staged; all waves' reads of cur done
    cur ^= 1;
  }

  const int er = (lane >> 4) * 4, ec = lane & 15;
#pragma unroll
  for (int mt = 0; mt < 4; ++mt) {
#pragma unroll
    for (int nt = 0; nt < 4; ++nt) {
#pragma unroll
      for (int i = 0; i < 4; ++i) {
        int r = bm * 128 + wr * 64 + mt * 16 + er + i;
        int c = bn * 128 + wc * 64 + nt * 16 + ec;
        float v = acc[mt][nt][i];
        if constexpr (MODE == 0) {
          int bb = r >> 11, t = r & 2047;
          ((unsigned short*)Cout)[((size_t)bb * LPAD + 3 + t) * DIM + c] = f2bf(v + bias[c]);
        } else if constexpr (MODE == 1) {
          // split-K partial: rows < M2P always valid in part buffer
          if (c < 48) ((float*)Cout)[((size_t)ks * M2P + r) * 48 + c] = v;
        } else {
          if (r < M2) ((float*)Cout)[(size_t)r * DMODEL + c] = v + bias[c];
        }
      }
    }
  }
}

// ---------------- reduce split-K partials -> xdbl (deterministic, no atomics) ----------
__global__ __launch_bounds__(256) void reduce_xdbl(const float* __restrict__ part,
                                                   float* __restrict__ xdbl) {
  int i = blockIdx.x * 256 + threadIdx.x;     // float4 index over [M2][48]
  if (i >= 196896) return;                    // 16408*48/4
  float4 s = make_float4(0.f, 0.f, 0.f, 0.f);
#pragma unroll
  for (int ks = 0; ks < 8; ++ks) {
    float4 v = *(const float4*)(part + (size_t)ks * M2P * 48 + (size_t)i * 4);
    s.x += v.x; s.y += v.y; s.z += v.z; s.w += v.w;
  }
  *(float4*)(xdbl + (size_t)i * 4) = s;
}

// ---------------- delta precompute: softplus(d_raw @ W_dt.T + b_dt) -> bf16 ----------------
__global__ __launch_bounds__(256) void delta_kernel(const float* __restrict__ xdbl,
                                                    const float* __restrict__ W_dt,
                                                    const float* __restrict__ b_dt,
                                                    unsigned short* __restrict__ delta) {
  const int d = blockIdx.y * 256 + threadIdx.x;
  const int r0 = blockIdx.x * 8;
  float wv[16];
  const float4* wp = (const float4*)(W_dt + (size_t)d * 16);
#pragma unroll
  for (int q = 0; q < 4; ++q) {
    float4 t = wp[q];
    wv[q * 4 + 0] = t.x; wv[q * 4 + 1] = t.y; wv[q * 4 + 2] = t.z; wv[q * 4 + 3] = t.w;
  }
  const float bd = b_dt[d];
#pragma unroll
  for (int j = 0; j < 8; ++j) {
    const float* dr = xdbl + (size_t)(r0 + j) * 48;   // uniform -> s_load
    float z0 = bd, z1 = 0.f, z2 = 0.f, z3 = 0.f;
#pragma unroll
    for (int n = 0; n < 16; n += 4) {
      z0 = fmaf(dr[n + 0], wv[n + 0], z0);
      z1 = fmaf(dr[n + 1], wv[n + 1], z1);
      z2 = fmaf(dr[n + 2], wv[n + 2], z2);
      z3 = fmaf(dr[n + 3], wv[n + 3], z3);
    }
    float z = (z0 + z1) + (z2 + z3);
    float dl = (z > 20.f) ? z : __logf(1.f + __expf(z));
    delta[(size_t)(r0 + j) * DIM + d] = f2bf(dl);
  }
}

// ---------------- chunked scan, pass 1: per-chunk (sumd, q) -> bf16 ----------------
__global__ __launch_bounds__(256) void scan_pass1(const unsigned short* __restrict__ xc,
                                                  const unsigned short* __restrict__ dl,
                                                  const float* __restrict__ xd,
                                                  unsigned short* __restrict__ sdbuf,
                                                  unsigned short* __restrict__ qbuf) {
  const int wid = __builtin_amdgcn_readfirstlane((int)(threadIdx.x >> 6));
  const int lane = threadIdx.x & 63;
  const int W = blockIdx.x * 4 + wid;
  const int dg = W & 31;
  const int rest = W >> 5;
  const int c = rest % NCH;
  const int b = rest / NCH;
  const int d = dg * 64 + lane;
  const int t0 = c * CS;
  const int nst = (t0 + CS <= LC) ? CS : (LC - t0);

  float2v A2L[8];
#pragma unroll
  for (int i = 0; i < 8; ++i)
    A2L[i] = (float2v){AeT[2 * i] * LOG2E, AeT[2 * i + 1] * LOG2E};

  float2v h2[8];
#pragma unroll
  for (int i = 0; i < 8; ++i) h2[i] = (float2v){0.f, 0.f};
  float sumd = 0.f;

  const size_t row0 = (size_t)b * LC + t0;
  const float* xdb = xd + row0 * 48 + 16;            // B cols (uniform -> s_load)
  const unsigned short* xcp = xc + row0 * DIM + d;
  const unsigned short* dp  = dl + row0 * DIM + d;

  auto body = [&](int s) {
    float2v Bv[8];
#pragma unroll
    for (int j = 0; j < 8; ++j) Bv[j] = *(const float2v*)(xdb + (size_t)s * 48 + 2 * j);
    float dlt = bf2f(dp[(size_t)s * DIM]);
    float xcv = bf2f(xcp[(size_t)s * DIM]);
    sumd += dlt;
    float2v dlt2 = (float2v){dlt, dlt};
    float2v xcv2 = (float2v){xcv, xcv};
#pragma unroll
    for (int i = 0; i < 8; ++i) {
      float2v arg = pk_mul_vv(dlt2, A2L[i]);
      float e0 = exp2_raw(arg.x), e1 = exp2_raw(arg.y);
      float2v e2 = (float2v){e0, e1};
      h2[i] = pk_fma_vvv(h2[i], e2, pk_mul_sv(Bv[i], xcv2));
    }
  };

  if (nst == CS) {
#pragma unroll
    for (int s = 0; s < CS; ++s) body(s);
  } else {
    for (int s = 0; s < nst; ++s) body(s);
  }

  sdbuf[((size_t)(b * NCH + c) << 11) + d] = f2bf(sumd);
  const size_t base = ((size_t)(b * NCH + c) * 16) * 2048 + d;
#pragma unroll
  for (int i = 0; i < 8; ++i) {
    qbuf[base + ((size_t)(2 * i) << 11)]     = f2bf(h2[i].x);
    qbuf[base + ((size_t)(2 * i + 1) << 11)] = f2bf(h2[i].y);
  }
}

// ---------------- boundary scan: 1 lane per (b,d,n); h across chunks, h_init over q ----
__global__ __launch_bounds__(256) void scan_boundary(const unsigned short* __restrict__ sdbuf,
                                                     unsigned short* __restrict__ qbuf) {
  const int tid = threadIdx.x;
  const int n = tid >> 4;                          // 0..15
  const int d = blockIdx.x * 16 + (tid & 15);      // 0..2047
  const int b = blockIdx.y;
  const float aL = AeT[n] * LOG2E;
  float h = 0.f;
  for (int c = 0; c < NCH; ++c) {
    const size_t sbase = ((size_t)(b * NCH + c) << 11);
    const float sd = bf2f(sdbuf[sbase + d]);
    const size_t base = (sbase << 4) + ((size_t)n << 11) + d;
    const float qv = bf2f(qbuf[base]);
    const float Pv = exp2_raw(sd * aL);
    qbuf[base] = f2bf(h);                          // h at chunk start
    h = fmaf(Pv, h, qv);
  }
}

// ---------------- chunked scan, pass 2: recompute with h_init, emit y ----------------
// NOTE: y aliases dl (in-place, same [r][d] layout); only the owning thread touches
// each element and reads precede the store for that row.
__global__ __launch_bounds__(256) void scan_pass2(const unsigned short* __restrict__ xc,
                                                  const unsigned short* __restrict__ dl,
                                                  const float* __restrict__ xd,
                                                  const unsigned short* __restrict__ hinit,
                                                  unsigned short* __restrict__ y) {
  const int wid = __builtin_amdgcn_readfirstlane((int)(threadIdx.x >> 6));
  const int lane = threadIdx.x & 63;
  const int W = blockIdx.x * 4 + wid;
  const int dg = W & 31;
  const int rest = W >> 5;
  const int c = rest % NCH;
  const int b = rest / NCH;
  const int d = dg * 64 + lane;
  const int t0 = c * CS;
  const int nst = (t0 + CS <= LC) ? CS : (LC - t0);

  float2v A2L[8];
#pragma unroll
  for (int i = 0; i < 8; ++i)
    A2L[i] = (float2v){AeT[2 * i] * LOG2E, AeT[2 * i + 1] * LOG2E};

  const size_t base = ((size_t)(b * NCH + c) * 16) * 2048 + d;
  float2v h2[8];
#pragma unroll
  for (int i = 0; i < 8; ++i)
    h2[i] = (float2v){bf2f(hinit[base + ((size_t)(2 * i) << 11)]),
                      bf2f(hinit[base + ((size_t)(2 * i + 1) << 11)])};

  const size_t row0 = (size_t)b * LC + t0;
  const float* xdb = xd + row0 * 48 + 16;            // B at [j], C at [16+j]
  const unsigned short* xcp = xc + row0 * DIM + d;
  const unsigned short* dp  = dl + row0 * DIM + d;
  unsigned short* yp = y + row0 * DIM + d;

  auto body = [&](int s) {
    float2v Bv[8], Cv[8];
#pragma unroll
    for (int j = 0; j < 8; ++j) {
      Bv[j] = *(const float2v*)(xdb + (size_t)s * 48 + 2 * j);
      Cv[j] = *(const float2v*)(xdb + (size_t)s * 48 + 16 + 2 * j);
    }
    float dlt = bf2f(dp[(size_t)s * DIM]);
    float xcv = bf2f(xcp[(size_t)s * DIM]);
    float2v dlt2 = (float2v){dlt, dlt};
    float2v xcv2 = (float2v){xcv, xcv};
    float2v y2[4];
#pragma unroll
    for (int i = 0; i < 4; ++i) y2[i] = (float2v){0.f, 0.f};
#pragma unroll
    for (int i = 0; i < 8; ++i) {
      float2v arg = pk_mul_vv(dlt2, A2L[i]);
      float e0 = exp2_raw(arg.x), e1 = exp2_raw(arg.y);
      float2v e2 = (float2v){e0, e1};
      h2[i] = pk_fma_vvv(h2[i], e2, pk_mul_sv(Bv[i], xcv2));
      y2[i & 3] = pk_fma_vsv(h2[i], Cv[i], y2[i & 3]);
    }
    float2v s01 = pk_add_vv(y2[0], y2[1]);
    float2v s23 = pk_add_vv(y2[2], y2[3]);
    float2v st = pk_add_vv(s01, s23);
    yp[(size_t)s * DIM] = f2bf(st.x + st.y);
  };

  if (nst == CS) {
#pragma unroll
    for (int s = 0; s < CS; ++s) body(s);
  } else {
    for (int s = 0; s < nst; ++s) body(s);
  }
}

// ---------------- launch ----------------
extern "C" void kernel_launch(void* const* d_in, const int* in_sizes, int n_in,
                              void* d_out, int out_size, void* d_ws, size_t ws_size,
                              hipStream_t stream) {
  const float* x      = (const float*)d_in[0];
  const float* W_in   = (const float*)d_in[1];
  const float* b_in   = (const float*)d_in[2];
  const float* conv_w = (const float*)d_in[3];
  const float* conv_b = (const float*)d_in[4];
  const float* W_x    = (const float*)d_in[5];
  const float* W_dt   = (const float*)d_in[6];
  const float* b_dt   = (const float*)d_in[7];
  const float* W_out  = (const float*)d_in[8];
  const float* b_out  = (const float*)d_in[9];

  char* w = (char*)d_ws;
  // region 0 (67.63 MB): xp (LPAD layout) -> delta [M2P][DIM] -> y (in-place over delta)
  unsigned short* xp    = (unsigned short*)w;
  unsigned short* delta = (unsigned short*)w;
  unsigned short* ybuf  = (unsigned short*)w;
  size_t off = (size_t)M2P * DIM * 2;                                  // 67,633,152
  unsigned short* xcb  = (unsigned short*)(w + off); off += (size_t)M2P * DIM * 2;
  size_t xA_off = off;                                                 // 135,266,304
  unsigned short* xA   = (unsigned short*)(w + off); off += (size_t)16384 * 1024 * 2;
  unsigned short* wInB = (unsigned short*)(w + off); off += (size_t)2048 * 1024 * 2;
  unsigned short* wOutB= (unsigned short*)(w + off); off += (size_t)1024 * 2048 * 2;
  unsigned short* wXB  = (unsigned short*)(w + off); off += (size_t)128 * 2048 * 2;
  float* xdbl          = (float*)(w + off);          off += (size_t)M2 * 48 * 4;
  // xA region (37.5 MB, dead after gemm<0>) reused twice:
  //  1) split-K partials (8 * M2P * 48 * 4 = 25.4 MB) between gemm<1> and reduce
  //  2) sdbuf (2.13 MB) + qbuf (34.08 MB) bf16 from scan_pass1 onward
  float* part           = (float*)(w + xA_off);
  unsigned short* sdbuf = (unsigned short*)(w + xA_off);
  unsigned short* qbuf  = (unsigned short*)(w + xA_off + (size_t)B8 * NCH * 2048 * 2);
  (void)ws_size; (void)in_sizes; (void)n_in; (void)out_size;

  init_kernel<<<10336, 256, 0, stream>>>(x, W_in, W_out, W_x, xA, wInB, wOutB, wXB, xp);

  // gemm<0>: 128 bm tiles exact
  gemm_bt<0, 128, 16, 16, 0, 0><<<2048, 256, 0, stream>>>(xA, wInB, b_in, xp, 1024);
  conv_kernel<<<dim3(129, B8), 256, 0, stream>>>(xp, conv_w, conv_b, xcb);
  // gemm<1>: split-K=8 (ks = gid&7 == XCD), partials -> part, then deterministic reduce
  gemm_bt<1, 129, 1, 0, 0, 1><<<1032, 256, 0, stream>>>(xcb, wXB, nullptr, part, 2048);
  reduce_xdbl<<<770, 256, 0, stream>>>(part, xdbl);
  delta_kernel<<<dim3(2051, 8), 256, 0, stream>>>(xdbl, W_dt, b_dt, delta);

  scan_pass1<<<4160, 256, 0, stream>>>(xcb, delta, xdbl, sdbuf, qbuf);
  scan_boundary<<<dim3(128, B8), 256, 0, stream>>>(sdbuf, qbuf);
  scan_pass2<<<4160, 256, 0, stream>>>(xcb, delta, xdbl, qbuf, ybuf);

  // gemm<2>: banded 1024 + 8 integrated tail blocks (bm=128, bn=0..7)
  gemm_bt<2, 129, 8, 16, 1, 0><<<1032, 256, 0, stream>>>(ybuf, wOutB, b_out, (float*)d_out, 2048);
}